// Round 1
// baseline (3947.593 us; speedup 1.0000x reference)
//
#include <hip/hip_runtime.h>

typedef unsigned int u32;
typedef unsigned short u16;
typedef unsigned char u8;

typedef __bf16 bf16_t;
typedef bf16_t bf16x8 __attribute__((ext_vector_type(8)));
typedef float f32x4 __attribute__((ext_vector_type(4)));

#define NROW 8192
#define HID 512
#define DIN 256

__device__ __forceinline__ u16 f2b(float f) {
    u32 u = __float_as_uint(f);
    u32 r = (u + 0x7fffu + ((u >> 16) & 1u)) >> 16;
    return (u16)r;
}
__device__ __forceinline__ float b2f(u16 h) {
    return __uint_as_float(((u32)h) << 16);
}
__device__ __forceinline__ f32x4 zero4() {
    f32x4 z = {0.f, 0.f, 0.f, 0.f};
    return z;
}

// ---------------- adj dtype sniffing ----------------
// mode 0: int32 (0/1), 1: float32 (0/1.0f), 2: bf16 (0/0x3f80), 3: bytes (bool8)
__global__ void sniff_adj(const u32* __restrict__ adj, int* __restrict__ mode) {
    if (threadIdx.x != 0) return;
    int all01 = 1, allf32 = 1, allbf = 1;
    for (int i = 0; i < 1024; i++) {
        u32 w = adj[i];
        if (w > 1u) all01 = 0;
        if (w != 0u && w != 0x3f800000u) allf32 = 0;
    }
    const u16* h = (const u16*)adj;
    for (int i = 0; i < 2048; i++) {
        u16 v = h[i];
        if (v != 0 && v != 0x3f80u) allbf = 0;
    }
    mode[0] = all01 ? 0 : (allf32 ? 1 : (allbf ? 2 : 3));
}

// build 1-bit adjacency mask: bits[row*256 + w] packs cols w*32..w*32+31
__global__ __launch_bounds__(256) void build_bits(const void* __restrict__ adj,
                                                  const int* __restrict__ mode,
                                                  u32* __restrict__ bits) {
    int row = blockIdx.x;
    int t = threadIdx.x;
    int lane = t & 63, wv = t >> 6;
    int md = *mode;
    for (int c0 = 0; c0 < NROW; c0 += 256) {
        int c = c0 + t;
        size_t idx = (size_t)row * NROW + c;
        bool nz;
        if (md == 0)      nz = ((const u32*)adj)[idx] != 0u;
        else if (md == 1) nz = ((const float*)adj)[idx] != 0.f;
        else if (md == 2) nz = ((const u16*)adj)[idx] != 0;
        else              nz = ((const u8*)adj)[idx] != 0;
        unsigned long long bm = __ballot(nz);
        if (lane == 0) {
            int w = row * 256 + (c0 >> 5) + wv * 2;
            bits[w] = (u32)bm;
            bits[w + 1] = (u32)(bm >> 32);
        }
    }
}

// ---------------- conversions ----------------
__global__ __launch_bounds__(256) void convert_f32_bf16(const float* __restrict__ in,
                                                        u16* __restrict__ out, int n) {
    int i = blockIdx.x * 256 + threadIdx.x;
    if (i < n) out[i] = f2b(in[i]);
}

// W [K,N] f32 -> Wt [N,K] bf16
__global__ __launch_bounds__(256) void convert_wt(const float* __restrict__ W,
                                                  u16* __restrict__ Wt, int K, int N) {
    int tid = blockIdx.x * 256 + threadIdx.x;
    if (tid >= K * N) return;
    int n = tid / K, k = tid - n * K;
    Wt[tid] = f2b(W[(size_t)k * N + n]);
}

// v [8192,512] bf16 -> vt [512,8192] bf16
__global__ __launch_bounds__(256) void transpose_v(const u16* __restrict__ in,
                                                   u16* __restrict__ out) {
    __shared__ u16 tile[64][65];
    int c0 = blockIdx.x * 64;   // col block in input (HID)
    int r0 = blockIdx.y * 64;   // row block (NROW)
    int t = threadIdx.x;
#pragma unroll
    for (int i = 0; i < 16; i++) {
        int idx = t + i * 256;
        int rr = idx >> 6, cc = idx & 63;
        tile[rr][cc] = in[(size_t)(r0 + rr) * HID + c0 + cc];
    }
    __syncthreads();
#pragma unroll
    for (int i = 0; i < 16; i++) {
        int idx = t + i * 256;
        int rr = idx >> 6, cc = idx & 63;
        out[(size_t)(c0 + rr) * NROW + r0 + cc] = tile[cc][rr];
    }
}

// ---------------- GEMM: C[M,N] = A[M,K] * Bt[N,K]^T + bias ----------------
// A, Bt bf16 row-major; optional f32 and/or bf16 outputs; optional relu.
__global__ __launch_bounds__(256, 2) void gemm_tn(const u16* __restrict__ A,
                                                  const u16* __restrict__ Bt,
                                                  const float* __restrict__ bias,
                                                  float* __restrict__ outF,
                                                  u16* __restrict__ outH,
                                                  int relu, int M, int N, int K) {
    int lane = threadIdx.x & 63;
    int wave = threadIdx.x >> 6;
    int l15 = lane & 15, lg = lane >> 4;
    int wr = wave >> 1, wc = wave & 1;
    int row0 = blockIdx.y * 128 + wr * 64;
    int col0 = blockIdx.x * 128 + wc * 64;
    const u16* ap = A + (size_t)(row0 + l15) * K + lg * 8;
    const u16* bp = Bt + (size_t)(col0 + l15) * K + lg * 8;
    f32x4 acc[4][4];
#pragma unroll
    for (int i = 0; i < 4; i++)
#pragma unroll
        for (int j = 0; j < 4; j++) acc[i][j] = zero4();

    for (int kk = 0; kk < K; kk += 32) {
        bf16x8 af[4], bfr[4];
#pragma unroll
        for (int f = 0; f < 4; f++)
            af[f] = *(const bf16x8*)(ap + (size_t)f * 16 * K + kk);
#pragma unroll
        for (int f = 0; f < 4; f++)
            bfr[f] = *(const bf16x8*)(bp + (size_t)f * 16 * K + kk);
#pragma unroll
        for (int i = 0; i < 4; i++)
#pragma unroll
            for (int j = 0; j < 4; j++)
                acc[i][j] = __builtin_amdgcn_mfma_f32_16x16x32_bf16(af[i], bfr[j],
                                                                   acc[i][j], 0, 0, 0);
    }
#pragma unroll
    for (int j = 0; j < 4; j++) {
        int col = col0 + j * 16 + l15;
        float bv = bias[col];
#pragma unroll
        for (int i = 0; i < 4; i++) {
#pragma unroll
            for (int r = 0; r < 4; r++) {
                int row = row0 + i * 16 + lg * 4 + r;
                float v = acc[i][j][r] + bv;
                if (relu) v = fmaxf(v, 0.f);
                size_t o = (size_t)row * N + col;
                if (outF) outF[o] = v;
                if (outH) outH[o] = f2b(v);
            }
        }
    }
}

// ---------------- fused flash attention with bitmask ----------------
// one wave handles 16 query rows over the full KV range (KV tile = 64)
__global__ __launch_bounds__(256, 2) void attn_kernel(const u16* __restrict__ Q,
                                                      const u16* __restrict__ Km,
                                                      const u16* __restrict__ VT,
                                                      const u32* __restrict__ bits,
                                                      u16* __restrict__ O16) {
    __shared__ u16 plds[4][16 * 64];
    int lane = threadIdx.x & 63, wave = threadIdx.x >> 6;
    int l15 = lane & 15, lg = lane >> 4;
    int qbase = (blockIdx.x * 4 + wave) * 16;
    u16* myp = plds[wave];

    f32x4 acc[32];
#pragma unroll
    for (int i = 0; i < 32; i++) acc[i] = zero4();
    float m[4] = {-1e30f, -1e30f, -1e30f, -1e30f};
    float lsum[4] = {0.f, 0.f, 0.f, 0.f};

    const u16* qp = Q + (size_t)(qbase + l15) * HID + lg * 8;
    const float scale = 0.04419417382415922f;  // 1/sqrt(512)

    for (int kv0 = 0; kv0 < NROW; kv0 += 64) {
        // S = Q(16x512) * K^T(512x64)
        f32x4 s[4];
#pragma unroll
        for (int f = 0; f < 4; f++) s[f] = zero4();
        for (int kk = 0; kk < HID; kk += 32) {
            bf16x8 aq = *(const bf16x8*)(qp + kk);
#pragma unroll
            for (int f = 0; f < 4; f++) {
                bf16x8 bk = *(const bf16x8*)(Km + (size_t)(kv0 + f * 16 + l15) * HID + kk + lg * 8);
                s[f] = __builtin_amdgcn_mfma_f32_16x16x32_bf16(aq, bk, s[f], 0, 0, 0);
            }
        }
        // load adjacency bits: rows qbase+lg*4+r, cols kv0..kv0+63
        u32 w0[4], w1[4];
#pragma unroll
        for (int r = 0; r < 4; r++) {
            const u32* wp = bits + (size_t)(qbase + lg * 4 + r) * 256 + (kv0 >> 5);
            w0[r] = wp[0];
            w1[r] = wp[1];
        }
        // mask + scale
        float pv[4][4];
        float mx[4] = {-1e30f, -1e30f, -1e30f, -1e30f};
#pragma unroll
        for (int f = 0; f < 4; f++) {
            int c = f * 16 + l15;
#pragma unroll
            for (int r = 0; r < 4; r++) {
                u32 w = (c < 32) ? w0[r] : w1[r];
                bool bit = (w >> (c & 31)) & 1u;
                float sv = bit ? s[f][r] * scale : -1e30f;
                pv[f][r] = sv;
                mx[r] = fmaxf(mx[r], sv);
            }
        }
        // row max across the 16 lanes of each group
#pragma unroll
        for (int r = 0; r < 4; r++) {
#pragma unroll
            for (int off = 8; off; off >>= 1)
                mx[r] = fmaxf(mx[r], __shfl_xor(mx[r], off, 64));
        }
        float csc[4];
        bool nochg = true;
#pragma unroll
        for (int r = 0; r < 4; r++) {
            float mn = fmaxf(m[r], mx[r]);
            csc[r] = __expf(m[r] - mn);
            m[r] = mn;
            nochg = nochg && (csc[r] == 1.f);
        }
        // exponentials (masked -> exact 0)
#pragma unroll
        for (int f = 0; f < 4; f++)
#pragma unroll
            for (int r = 0; r < 4; r++)
                pv[f][r] = (pv[f][r] < -1e29f) ? 0.f : __expf(pv[f][r] - m[r]);
        // row sums
#pragma unroll
        for (int r = 0; r < 4; r++) {
            float rs = pv[0][r] + pv[1][r] + pv[2][r] + pv[3][r];
#pragma unroll
            for (int off = 8; off; off >>= 1) rs += __shfl_xor(rs, off, 64);
            lsum[r] = lsum[r] * csc[r] + rs;
        }
        // rescale accumulator (skip when no new max anywhere in wave)
        if (!__all(nochg ? 1 : 0)) {
#pragma unroll
            for (int i = 0; i < 32; i++) {
                f32x4 a = acc[i];
                a[0] *= csc[0]; a[1] *= csc[1]; a[2] *= csc[2]; a[3] *= csc[3];
                acc[i] = a;
            }
        }
        // P (D-layout) -> LDS -> A-layout bf16 fragments
#pragma unroll
        for (int f = 0; f < 4; f++)
#pragma unroll
            for (int r = 0; r < 4; r++)
                myp[(lg * 4 + r) * 64 + f * 16 + l15] = f2b(pv[f][r]);
        asm volatile("s_waitcnt lgkmcnt(0)" ::: "memory");
        bf16x8 pa0 = *(const bf16x8*)(myp + l15 * 64 + lg * 8);
        bf16x8 pa1 = *(const bf16x8*)(myp + l15 * 64 + 32 + lg * 8);
        // O += P(16x64) * V(64x512)
#pragma unroll
        for (int cf = 0; cf < 32; cf++) {
            bf16x8 b0 = *(const bf16x8*)(VT + (size_t)(cf * 16 + l15) * NROW + kv0 + lg * 8);
            acc[cf] = __builtin_amdgcn_mfma_f32_16x16x32_bf16(pa0, b0, acc[cf], 0, 0, 0);
        }
#pragma unroll
        for (int cf = 0; cf < 32; cf++) {
            bf16x8 b1 = *(const bf16x8*)(VT + (size_t)(cf * 16 + l15) * NROW + kv0 + 32 + lg * 8);
            acc[cf] = __builtin_amdgcn_mfma_f32_16x16x32_bf16(pa1, b1, acc[cf], 0, 0, 0);
        }
    }
    // normalize + store bf16
#pragma unroll
    for (int cf = 0; cf < 32; cf++) {
        int col = cf * 16 + l15;
#pragma unroll
        for (int r = 0; r < 4; r++) {
            int row = qbase + lg * 4 + r;
            O16[(size_t)row * HID + col] = f2b(acc[cf][r] / lsum[r]);
        }
    }
}

// ---------------- layernorm(a+b) ----------------
__global__ __launch_bounds__(256) void ln_add(const float* __restrict__ a,
                                              const float* __restrict__ b,
                                              const float* __restrict__ g,
                                              const float* __restrict__ be,
                                              float* __restrict__ outF,
                                              u16* __restrict__ outH) {
    int row = blockIdx.x, t = threadIdx.x;
    const float* ar = a + (size_t)row * HID;
    const float* br = b + (size_t)row * HID;
    float x0 = ar[t] + br[t];
    float x1 = ar[t + 256] + br[t + 256];
    float s = x0 + x1, s2 = x0 * x0 + x1 * x1;
#pragma unroll
    for (int off = 32; off; off >>= 1) {
        s += __shfl_xor(s, off, 64);
        s2 += __shfl_xor(s2, off, 64);
    }
    __shared__ float ls[4], ls2[4];
    int wv = t >> 6, ln = t & 63;
    if (ln == 0) { ls[wv] = s; ls2[wv] = s2; }
    __syncthreads();
    float S = ls[0] + ls[1] + ls[2] + ls[3];
    float S2 = ls2[0] + ls2[1] + ls2[2] + ls2[3];
    float mu = S * (1.f / 512.f);
    float var = S2 * (1.f / 512.f) - mu * mu;
    float inv = rsqrtf(var + 1e-5f);
    float y0 = (x0 - mu) * inv * g[t] + be[t];
    float y1 = (x1 - mu) * inv * g[t + 256] + be[t + 256];
    size_t o = (size_t)row * HID + t;
    if (outF) { outF[o] = y0; outF[o + 256] = y1; }
    if (outH) { outH[o] = f2b(y0); outH[o + 256] = f2b(y1); }
}

// ---------------- logits: out[row] = hfin[row,:] . Ws + bs ----------------
__global__ __launch_bounds__(256) void logits_k(const u16* __restrict__ hfin,
                                                const float* __restrict__ Ws,
                                                const float* __restrict__ bs,
                                                float* __restrict__ out) {
    int row = blockIdx.x * 4 + (threadIdx.x >> 6);
    int lane = threadIdx.x & 63;
    const u16* hp = hfin + (size_t)row * HID + lane * 8;
    float sum = 0.f;
#pragma unroll
    for (int j = 0; j < 8; j++) sum += b2f(hp[j]) * Ws[lane * 8 + j];
#pragma unroll
    for (int off = 32; off; off >>= 1) sum += __shfl_xor(sum, off, 64);
    if (lane == 0) out[row] = sum + bs[0];
}

// ---------------- host launcher ----------------
extern "C" void kernel_launch(void* const* d_in, const int* in_sizes, int n_in,
                              void* d_out, int out_size, void* d_ws, size_t ws_size,
                              hipStream_t stream) {
    const float* x   = (const float*)d_in[0];
    const void*  adj = d_in[1];
    const float* Win = (const float*)d_in[2];
    const float* b_in= (const float*)d_in[3];
    const float* Wq  = (const float*)d_in[4];
    const float* bq  = (const float*)d_in[5];
    const float* Wk  = (const float*)d_in[6];
    const float* bk  = (const float*)d_in[7];
    const float* Wv  = (const float*)d_in[8];
    const float* bv  = (const float*)d_in[9];
    const float* Wo  = (const float*)d_in[10];
    const float* bo  = (const float*)d_in[11];
    const float* Ws  = (const float*)d_in[12];
    const float* bs  = (const float*)d_in[13];
    const float* g1  = (const float*)d_in[14];
    const float* be1 = (const float*)d_in[15];
    const float* g2  = (const float*)d_in[16];
    const float* be2 = (const float*)d_in[17];
    const float* Wf1 = (const float*)d_in[18];
    const float* bf1 = (const float*)d_in[19];
    const float* Wf2 = (const float*)d_in[20];
    const float* bf2 = (const float*)d_in[21];

    char* ws = (char*)d_ws;
    // ws layout (bytes)
    const size_t X16   = 0;                    // 4 MB  (8192x256 bf16)
    const size_t WINT  = 4194304;              // 256 KB
    const size_t WQT   = WINT + 262144;
    const size_t WKT   = WQT + 524288;
    const size_t WVT   = WKT + 524288;
    const size_t WOT   = WVT + 524288;
    const size_t WF1T  = WOT + 524288;
    const size_t WF2T  = WF1T + 524288;
    const size_t MODE  = WF2T + 524288;        // 256 B
    const size_t BITS  = MODE + 256;           // 8 MB
    const size_t H16   = BITS + 8388608;       // 8 MB
    const size_t HF32  = H16 + 8388608;        // 16 MB
    const size_t Q16   = HF32 + 16777216;      // 8 MB
    const size_t K16   = Q16 + 8388608;        // 8 MB
    const size_t V16   = K16 + 8388608;        // 8 MB
    const size_t VT16  = V16 + 8388608;        // 8 MB
    const size_t H2    = VT16 + 8388608;       // 8 MB
    const size_t HN32  = H2 + 8388608;         // 16 MB
    const size_t HN16  = HN32 + 16777216;      // 8 MB  -> total ~103 MB
    // reuses (dead buffers)
    const size_t OP32  = Q16;   // 16 MB spans Q16+K16 (dead after attention)
    const size_t FF1   = H16;   // dead after QKV gemms
    const size_t FF2   = HF32;  // dead after LN1
    const size_t HFIN  = V16;   // dead after transpose

    u16* pX16  = (u16*)(ws + X16);
    u16* pWinT = (u16*)(ws + WINT);
    u16* pWqT  = (u16*)(ws + WQT);
    u16* pWkT  = (u16*)(ws + WKT);
    u16* pWvT  = (u16*)(ws + WVT);
    u16* pWoT  = (u16*)(ws + WOT);
    u16* pWf1T = (u16*)(ws + WF1T);
    u16* pWf2T = (u16*)(ws + WF2T);
    int* pMode = (int*)(ws + MODE);
    u32* pBits = (u32*)(ws + BITS);
    u16* pH16  = (u16*)(ws + H16);
    float* pHF32 = (float*)(ws + HF32);
    u16* pQ16  = (u16*)(ws + Q16);
    u16* pK16  = (u16*)(ws + K16);
    u16* pV16  = (u16*)(ws + V16);
    u16* pVT16 = (u16*)(ws + VT16);
    u16* pH2   = (u16*)(ws + H2);
    float* pHN32 = (float*)(ws + HN32);
    u16* pHN16 = (u16*)(ws + HN16);
    float* pOP32 = (float*)(ws + OP32);
    u16* pFF1  = (u16*)(ws + FF1);
    float* pFF2 = (float*)(ws + FF2);
    u16* pHFIN = (u16*)(ws + HFIN);

    // 1. adjacency: sniff dtype, build bitmask
    sniff_adj<<<1, 64, 0, stream>>>((const u32*)adj, pMode);
    build_bits<<<NROW, 256, 0, stream>>>(adj, pMode, pBits);

    // 2. conversions
    convert_f32_bf16<<<(NROW * DIN) / 256, 256, 0, stream>>>(x, pX16, NROW * DIN);
    convert_wt<<<(DIN * HID + 255) / 256, 256, 0, stream>>>(Win, pWinT, DIN, HID);
    convert_wt<<<(HID * HID + 255) / 256, 256, 0, stream>>>(Wq, pWqT, HID, HID);
    convert_wt<<<(HID * HID + 255) / 256, 256, 0, stream>>>(Wk, pWkT, HID, HID);
    convert_wt<<<(HID * HID + 255) / 256, 256, 0, stream>>>(Wv, pWvT, HID, HID);
    convert_wt<<<(HID * HID + 255) / 256, 256, 0, stream>>>(Wo, pWoT, HID, HID);
    convert_wt<<<(HID * HID + 255) / 256, 256, 0, stream>>>(Wf1, pWf1T, HID, HID);
    convert_wt<<<(HID * HID + 255) / 256, 256, 0, stream>>>(Wf2, pWf2T, HID, HID);

    dim3 gproj(HID / 128, NROW / 128);  // (4, 64)

    // 3. h = x @ Win + b_in  (f32 + bf16)
    gemm_tn<<<gproj, 256, 0, stream>>>(pX16, pWinT, b_in, pHF32, pH16, 0, NROW, HID, DIN);
    // 4. q, k, v
    gemm_tn<<<gproj, 256, 0, stream>>>(pH16, pWqT, bq, nullptr, pQ16, 0, NROW, HID, HID);
    gemm_tn<<<gproj, 256, 0, stream>>>(pH16, pWkT, bk, nullptr, pK16, 0, NROW, HID, HID);
    gemm_tn<<<gproj, 256, 0, stream>>>(pH16, pWvT, bv, nullptr, pV16, 0, NROW, HID, HID);
    // 5. vt
    transpose_v<<<dim3(HID / 64, NROW / 64), 256, 0, stream>>>(pV16, pVT16);
    // 6. attention
    attn_kernel<<<NROW / 64, 256, 0, stream>>>(pQ16, pK16, pVT16, pBits, pH2);
    // 7. o-proj (f32)
    gemm_tn<<<gproj, 256, 0, stream>>>(pH2, pWoT, bo, pOP32, nullptr, 0, NROW, HID, HID);
    // 8. LN1: ln(h + oproj)
    ln_add<<<NROW, 256, 0, stream>>>(pHF32, pOP32, g1, be1, pHN32, pHN16);
    // 9. ff1 = relu(hn @ Wf1 + bf1)
    gemm_tn<<<gproj, 256, 0, stream>>>(pHN16, pWf1T, bf1, nullptr, pFF1, 1, NROW, HID, HID);
    // 10. ff2 = ff1 @ Wf2 + bf2 (f32)
    gemm_tn<<<gproj, 256, 0, stream>>>(pFF1, pWf2T, bf2, pFF2, nullptr, 0, NROW, HID, HID);
    // 11. LN2: ln(hn + ff2) -> bf16
    ln_add<<<NROW, 256, 0, stream>>>(pHN32, pFF2, g2, be2, nullptr, pHFIN);
    // 12. logits
    logits_k<<<NROW / 4, 256, 0, stream>>>(pHFIN, Ws, bs, (float*)d_out);
}

// Round 2
// 1508.836 us; speedup vs baseline: 2.6163x; 2.6163x over previous
//
#include <hip/hip_runtime.h>

typedef unsigned int u32;
typedef unsigned short u16;
typedef unsigned char u8;

typedef __bf16 bf16_t;
typedef bf16_t bf16x8 __attribute__((ext_vector_type(8)));
typedef float f32x4 __attribute__((ext_vector_type(4)));

#define NROW 8192
#define HID 512
#define DIN 256
#define LDQ 1536   // row stride of fused qkv buffer
#define NSPLIT 4
#define KVCH (NROW / NSPLIT)   // 2048

__device__ __forceinline__ u16 f2b(float f) {
    u32 u = __float_as_uint(f);
    u32 r = (u + 0x7fffu + ((u >> 16) & 1u)) >> 16;
    return (u16)r;
}
__device__ __forceinline__ float b2f(u16 h) {
    return __uint_as_float(((u32)h) << 16);
}
__device__ __forceinline__ f32x4 zero4() {
    f32x4 z = {0.f, 0.f, 0.f, 0.f};
    return z;
}

// ---------------- adj dtype sniffing ----------------
__global__ void sniff_adj(const u32* __restrict__ adj, int* __restrict__ mode) {
    if (threadIdx.x != 0) return;
    int all01 = 1, allf32 = 1, allbf = 1;
    for (int i = 0; i < 1024; i++) {
        u32 w = adj[i];
        if (w > 1u) all01 = 0;
        if (w != 0u && w != 0x3f800000u) allf32 = 0;
    }
    const u16* h = (const u16*)adj;
    for (int i = 0; i < 2048; i++) {
        u16 v = h[i];
        if (v != 0 && v != 0x3f80u) allbf = 0;
    }
    mode[0] = all01 ? 0 : (allf32 ? 1 : (allbf ? 2 : 3));
}

__global__ __launch_bounds__(256) void build_bits(const void* __restrict__ adj,
                                                  const int* __restrict__ mode,
                                                  u32* __restrict__ bits) {
    int row = blockIdx.x;
    int t = threadIdx.x;
    int lane = t & 63, wv = t >> 6;
    int md = *mode;
    for (int c0 = 0; c0 < NROW; c0 += 256) {
        int c = c0 + t;
        size_t idx = (size_t)row * NROW + c;
        bool nz;
        if (md == 0)      nz = ((const u32*)adj)[idx] != 0u;
        else if (md == 1) nz = ((const float*)adj)[idx] != 0.f;
        else if (md == 2) nz = ((const u16*)adj)[idx] != 0;
        else              nz = ((const u8*)adj)[idx] != 0;
        unsigned long long bm = __ballot(nz);
        if (lane == 0) {
            int w = row * 256 + (c0 >> 5) + wv * 2;
            bits[w] = (u32)bm;
            bits[w + 1] = (u32)(bm >> 32);
        }
    }
}

// ---------------- conversions ----------------
__global__ __launch_bounds__(256) void convert_f32_bf16(const float* __restrict__ in,
                                                        u16* __restrict__ out, int n) {
    int i = blockIdx.x * 256 + threadIdx.x;
    if (i < n) out[i] = f2b(in[i]);
}

// W [K,N] f32 -> Wt [N,K] bf16
__global__ __launch_bounds__(256) void convert_wt(const float* __restrict__ W,
                                                  u16* __restrict__ Wt, int K, int N) {
    int tid = blockIdx.x * 256 + threadIdx.x;
    if (tid >= K * N) return;
    int n = tid / K, k = tid - n * K;
    Wt[tid] = f2b(W[(size_t)k * N + n]);
}

__global__ void concat_bias(const float* __restrict__ bq, const float* __restrict__ bk,
                            const float* __restrict__ bv, float* __restrict__ out) {
    int i = blockIdx.x * 256 + threadIdx.x;
    if (i >= 1536) return;
    out[i] = i < 512 ? bq[i] : (i < 1024 ? bk[i - 512] : bv[i - 1024]);
}

// V (stride ldv) -> vt [512][8192]
__global__ __launch_bounds__(256) void transpose_v(const u16* __restrict__ in, int ldv,
                                                   u16* __restrict__ out) {
    __shared__ u16 tile[64][65];
    int c0 = blockIdx.x * 64;   // col block (HID)
    int r0 = blockIdx.y * 64;   // row block (NROW)
    int t = threadIdx.x;
#pragma unroll
    for (int i = 0; i < 16; i++) {
        int idx = t + i * 256;
        int rr = idx >> 6, cc = idx & 63;
        tile[rr][cc] = in[(size_t)(r0 + rr) * ldv + c0 + cc];
    }
    __syncthreads();
#pragma unroll
    for (int i = 0; i < 16; i++) {
        int idx = t + i * 256;
        int rr = idx >> 6, cc = idx & 63;
        out[(size_t)(c0 + rr) * NROW + r0 + cc] = tile[cc][rr];
    }
}

// ---------------- GEMM: C[M,ldo] = A[M,K](lda) * Bt[N,K]^T + bias ----------------
template <int WM, int WN>
__global__ __launch_bounds__(256, 2) void gemm_tn(const u16* __restrict__ A, int lda,
                                                  const u16* __restrict__ Bt,
                                                  const float* __restrict__ bias,
                                                  float* __restrict__ outF,
                                                  u16* __restrict__ outH, int ldo,
                                                  int relu, int K) {
    constexpr int AM = WM / 16, BN = WN / 16;
    int lane = threadIdx.x & 63;
    int wave = threadIdx.x >> 6;
    int l15 = lane & 15, lg = lane >> 4;
    int wr = wave >> 1, wc = wave & 1;
    int row0 = blockIdx.y * (2 * WM) + wr * WM;
    int col0 = blockIdx.x * (2 * WN) + wc * WN;
    const u16* ap = A + (size_t)(row0 + l15) * lda + lg * 8;
    const u16* bp = Bt + (size_t)(col0 + l15) * K + lg * 8;
    f32x4 acc[AM][BN];
#pragma unroll
    for (int i = 0; i < AM; i++)
#pragma unroll
        for (int j = 0; j < BN; j++) acc[i][j] = zero4();

    bf16x8 af_c[AM], bf_c[BN];
#pragma unroll
    for (int i = 0; i < AM; i++) af_c[i] = *(const bf16x8*)(ap + (size_t)i * 16 * lda);
#pragma unroll
    for (int j = 0; j < BN; j++) bf_c[j] = *(const bf16x8*)(bp + (size_t)j * 16 * K);

    for (int kk = 32; kk <= K; kk += 32) {
        bf16x8 af_n[AM], bf_n[BN];
        if (kk < K) {
#pragma unroll
            for (int i = 0; i < AM; i++)
                af_n[i] = *(const bf16x8*)(ap + (size_t)i * 16 * lda + kk);
#pragma unroll
            for (int j = 0; j < BN; j++)
                bf_n[j] = *(const bf16x8*)(bp + (size_t)j * 16 * K + kk);
        } else {
#pragma unroll
            for (int i = 0; i < AM; i++) af_n[i] = af_c[i];
#pragma unroll
            for (int j = 0; j < BN; j++) bf_n[j] = bf_c[j];
        }
#pragma unroll
        for (int i = 0; i < AM; i++)
#pragma unroll
            for (int j = 0; j < BN; j++)
                acc[i][j] = __builtin_amdgcn_mfma_f32_16x16x32_bf16(af_c[i], bf_c[j],
                                                                   acc[i][j], 0, 0, 0);
#pragma unroll
        for (int i = 0; i < AM; i++) af_c[i] = af_n[i];
#pragma unroll
        for (int j = 0; j < BN; j++) bf_c[j] = bf_n[j];
    }
#pragma unroll
    for (int j = 0; j < BN; j++) {
        int col = col0 + j * 16 + l15;
        float bv = bias[col];
#pragma unroll
        for (int i = 0; i < AM; i++) {
#pragma unroll
            for (int r = 0; r < 4; r++) {
                int row = row0 + i * 16 + lg * 4 + r;
                float v = acc[i][j][r] + bv;
                if (relu) v = fmaxf(v, 0.f);
                size_t o = (size_t)row * ldo + col;
                if (outF) outF[o] = v;
                if (outH) outH[o] = f2b(v);
            }
        }
    }
}

// ---------------- split-KV flash attention ----------------
// grid: 256 blocks = 64 q-blocks x 4 kv-splits (s = bid & 3 -> XCD affinity).
// block: 8 waves x 16 q rows = 128 q rows; each wave sweeps the block's 2048-col
// KV chunk. Writes unnormalized bf16 partial O + per-row (m, l).
__global__ __launch_bounds__(512, 2) void attn_kernel(const u16* __restrict__ QKV,
                                                      const u16* __restrict__ VT,
                                                      const u32* __restrict__ bits,
                                                      u16* __restrict__ Opart,
                                                      float* __restrict__ Mpart,
                                                      float* __restrict__ Lpart) {
    __shared__ u16 plds[8][1024];
    int lane = threadIdx.x & 63, wave = threadIdx.x >> 6;
    int l15 = lane & 15, lg = lane >> 4;
    int s = blockIdx.x & 3;
    int qb = blockIdx.x >> 2;
    int qbase = qb * 128 + wave * 16;
    u16* myp = plds[wave];

    const u16* Kp = QKV + 512;
    const u16* qp = QKV + (size_t)(qbase + l15) * LDQ + lg * 8;

    f32x4 acc[32];
#pragma unroll
    for (int i = 0; i < 32; i++) acc[i] = zero4();
    float m[4] = {-1e30f, -1e30f, -1e30f, -1e30f};
    float lsum[4] = {0.f, 0.f, 0.f, 0.f};
    const float scale = 0.04419417382415922f;  // 1/sqrt(512)

    int kvbeg = s * KVCH;
    for (int t = 0; t < KVCH / 64; ++t) {
        int kv0 = kvbeg + t * 64;
        // ---- S = Q(16x512) @ K^T(512x64), reg double-buffered ----
        const u16* kp = Kp + (size_t)(kv0 + l15) * LDQ + lg * 8;
        f32x4 sf[4];
#pragma unroll
        for (int f = 0; f < 4; f++) sf[f] = zero4();
        bf16x8 aq_c = *(const bf16x8*)qp;
        bf16x8 bk_c0 = *(const bf16x8*)(kp);
        bf16x8 bk_c1 = *(const bf16x8*)(kp + 16 * LDQ);
        bf16x8 bk_c2 = *(const bf16x8*)(kp + 32 * LDQ);
        bf16x8 bk_c3 = *(const bf16x8*)(kp + 48 * LDQ);
#pragma unroll
        for (int kk = 32; kk <= 512; kk += 32) {
            bf16x8 aq_n = aq_c, bk_n0 = bk_c0, bk_n1 = bk_c1, bk_n2 = bk_c2, bk_n3 = bk_c3;
            if (kk < 512) {
                aq_n = *(const bf16x8*)(qp + kk);
                bk_n0 = *(const bf16x8*)(kp + kk);
                bk_n1 = *(const bf16x8*)(kp + 16 * LDQ + kk);
                bk_n2 = *(const bf16x8*)(kp + 32 * LDQ + kk);
                bk_n3 = *(const bf16x8*)(kp + 48 * LDQ + kk);
            }
            sf[0] = __builtin_amdgcn_mfma_f32_16x16x32_bf16(aq_c, bk_c0, sf[0], 0, 0, 0);
            sf[1] = __builtin_amdgcn_mfma_f32_16x16x32_bf16(aq_c, bk_c1, sf[1], 0, 0, 0);
            sf[2] = __builtin_amdgcn_mfma_f32_16x16x32_bf16(aq_c, bk_c2, sf[2], 0, 0, 0);
            sf[3] = __builtin_amdgcn_mfma_f32_16x16x32_bf16(aq_c, bk_c3, sf[3], 0, 0, 0);
            aq_c = aq_n; bk_c0 = bk_n0; bk_c1 = bk_n1; bk_c2 = bk_n2; bk_c3 = bk_n3;
        }
        // ---- adjacency bits ----
        u32 w0[4], w1[4];
#pragma unroll
        for (int r = 0; r < 4; r++) {
            const u32* wp = bits + (size_t)(qbase + lg * 4 + r) * 256 + (kv0 >> 5);
            w0[r] = wp[0];
            w1[r] = wp[1];
        }
        // ---- mask + scale + online softmax ----
        float pv[4][4];
        float mx[4] = {-1e30f, -1e30f, -1e30f, -1e30f};
#pragma unroll
        for (int f = 0; f < 4; f++) {
            int c = f * 16 + l15;
#pragma unroll
            for (int r = 0; r < 4; r++) {
                u32 w = (c < 32) ? w0[r] : w1[r];
                bool bit = (w >> (c & 31)) & 1u;
                float sv = bit ? sf[f][r] * scale : -1e30f;
                pv[f][r] = sv;
                mx[r] = fmaxf(mx[r], sv);
            }
        }
#pragma unroll
        for (int r = 0; r < 4; r++) {
#pragma unroll
            for (int off = 8; off; off >>= 1)
                mx[r] = fmaxf(mx[r], __shfl_xor(mx[r], off, 64));
        }
        float csc[4];
        bool nochg = true;
#pragma unroll
        for (int r = 0; r < 4; r++) {
            float mn = fmaxf(m[r], mx[r]);
            csc[r] = __expf(m[r] - mn);
            m[r] = mn;
            nochg = nochg && (csc[r] == 1.f);
        }
#pragma unroll
        for (int f = 0; f < 4; f++)
#pragma unroll
            for (int r = 0; r < 4; r++)
                pv[f][r] = (pv[f][r] < -1e29f) ? 0.f : __expf(pv[f][r] - m[r]);
#pragma unroll
        for (int r = 0; r < 4; r++) {
            float rs = pv[0][r] + pv[1][r] + pv[2][r] + pv[3][r];
#pragma unroll
            for (int off = 8; off; off >>= 1) rs += __shfl_xor(rs, off, 64);
            lsum[r] = lsum[r] * csc[r] + rs;
        }
        if (!__all(nochg ? 1 : 0)) {
#pragma unroll
            for (int i = 0; i < 32; i++) {
                f32x4 a = acc[i];
                a[0] *= csc[0]; a[1] *= csc[1]; a[2] *= csc[2]; a[3] *= csc[3];
                acc[i] = a;
            }
        }
        // ---- P (D-layout) -> LDS -> A-layout fragments ----
#pragma unroll
        for (int f = 0; f < 4; f++)
#pragma unroll
            for (int r = 0; r < 4; r++)
                myp[(lg * 4 + r) * 64 + f * 16 + l15] = f2b(pv[f][r]);
        asm volatile("s_waitcnt lgkmcnt(0)" ::: "memory");
        __builtin_amdgcn_sched_barrier(0);
        bf16x8 pa0 = *(const bf16x8*)(myp + l15 * 64 + lg * 8);
        bf16x8 pa1 = *(const bf16x8*)(myp + l15 * 64 + 32 + lg * 8);
        // ---- O += P(16x64) @ V(64x512), prefetch one cf ahead ----
        bf16x8 vb0 = *(const bf16x8*)(VT + (size_t)l15 * NROW + kv0 + lg * 8);
        bf16x8 vb1 = *(const bf16x8*)(VT + (size_t)l15 * NROW + kv0 + 32 + lg * 8);
#pragma unroll
        for (int cf = 0; cf < 32; ++cf) {
            bf16x8 vn0 = vb0, vn1 = vb1;
            if (cf + 1 < 32) {
                const u16* vp = VT + (size_t)((cf + 1) * 16 + l15) * NROW + kv0 + lg * 8;
                vn0 = *(const bf16x8*)(vp);
                vn1 = *(const bf16x8*)(vp + 32);
            }
            acc[cf] = __builtin_amdgcn_mfma_f32_16x16x32_bf16(pa0, vb0, acc[cf], 0, 0, 0);
            acc[cf] = __builtin_amdgcn_mfma_f32_16x16x32_bf16(pa1, vb1, acc[cf], 0, 0, 0);
            vb0 = vn0; vb1 = vn1;
        }
    }
    // ---- write partials ----
    if (l15 == 0) {
#pragma unroll
        for (int r = 0; r < 4; r++) {
            size_t o = (size_t)s * NROW + qbase + lg * 4 + r;
            Mpart[o] = m[r];
            Lpart[o] = lsum[r];
        }
    }
#pragma unroll
    for (int cf = 0; cf < 32; cf++) {
        int col = cf * 16 + l15;
#pragma unroll
        for (int r = 0; r < 4; r++) {
            size_t row = (size_t)s * NROW + qbase + lg * 4 + r;
            Opart[row * HID + col] = f2b(acc[cf][r]);
        }
    }
}

// combine 4 split partials -> O16
__global__ __launch_bounds__(256) void attn_combine(const u16* __restrict__ Opart,
                                                    const float* __restrict__ Mpart,
                                                    const float* __restrict__ Lpart,
                                                    u16* __restrict__ O16) {
    int idx = blockIdx.x * 256 + threadIdx.x;
    int row = idx >> 6;
    int c8 = (idx & 63) << 3;
    float ms[NSPLIT], M = -1e30f;
#pragma unroll
    for (int s = 0; s < NSPLIT; s++) {
        ms[s] = Mpart[(size_t)s * NROW + row];
        M = fmaxf(M, ms[s]);
    }
    float w[NSPLIT], L = 0.f;
#pragma unroll
    for (int s = 0; s < NSPLIT; s++) {
        w[s] = __expf(ms[s] - M);
        L += Lpart[(size_t)s * NROW + row] * w[s];
    }
    float inv = 1.f / L;
    float o[8];
#pragma unroll
    for (int j = 0; j < 8; j++) o[j] = 0.f;
#pragma unroll
    for (int s = 0; s < NSPLIT; s++) {
        bf16x8 p = *(const bf16x8*)(Opart + ((size_t)s * NROW + row) * HID + c8);
#pragma unroll
        for (int j = 0; j < 8; j++) o[j] += (float)p[j] * w[s];
    }
    bf16x8 res;
#pragma unroll
    for (int j = 0; j < 8; j++) {
        u16 b = f2b(o[j] * inv);
        res[j] = *(bf16_t*)&b;
    }
    *(bf16x8*)(O16 + (size_t)row * HID + c8) = res;
}

// ---------------- layernorm(a+b) ----------------
__global__ __launch_bounds__(256) void ln_add(const float* __restrict__ a,
                                              const float* __restrict__ b,
                                              const float* __restrict__ g,
                                              const float* __restrict__ be,
                                              float* __restrict__ outF,
                                              u16* __restrict__ outH) {
    int row = blockIdx.x, t = threadIdx.x;
    const float* ar = a + (size_t)row * HID;
    const float* br = b + (size_t)row * HID;
    float x0 = ar[t] + br[t];
    float x1 = ar[t + 256] + br[t + 256];
    float s = x0 + x1, s2 = x0 * x0 + x1 * x1;
#pragma unroll
    for (int off = 32; off; off >>= 1) {
        s += __shfl_xor(s, off, 64);
        s2 += __shfl_xor(s2, off, 64);
    }
    __shared__ float ls[4], ls2[4];
    int wv = t >> 6, ln = t & 63;
    if (ln == 0) { ls[wv] = s; ls2[wv] = s2; }
    __syncthreads();
    float S = ls[0] + ls[1] + ls[2] + ls[3];
    float S2 = ls2[0] + ls2[1] + ls2[2] + ls2[3];
    float mu = S * (1.f / 512.f);
    float var = S2 * (1.f / 512.f) - mu * mu;
    float inv = rsqrtf(var + 1e-5f);
    float y0 = (x0 - mu) * inv * g[t] + be[t];
    float y1 = (x1 - mu) * inv * g[t + 256] + be[t + 256];
    size_t o = (size_t)row * HID + t;
    if (outF) { outF[o] = y0; outF[o + 256] = y1; }
    if (outH) { outH[o] = f2b(y0); outH[o + 256] = f2b(y1); }
}

// ---------------- logits ----------------
__global__ __launch_bounds__(256) void logits_k(const u16* __restrict__ hfin,
                                                const float* __restrict__ Ws,
                                                const float* __restrict__ bs,
                                                float* __restrict__ out) {
    int row = blockIdx.x * 4 + (threadIdx.x >> 6);
    int lane = threadIdx.x & 63;
    const u16* hp = hfin + (size_t)row * HID + lane * 8;
    float sum = 0.f;
#pragma unroll
    for (int j = 0; j < 8; j++) sum += b2f(hp[j]) * Ws[lane * 8 + j];
#pragma unroll
    for (int off = 32; off; off >>= 1) sum += __shfl_xor(sum, off, 64);
    if (lane == 0) out[row] = sum + bs[0];
}

// ---------------- host launcher ----------------
extern "C" void kernel_launch(void* const* d_in, const int* in_sizes, int n_in,
                              void* d_out, int out_size, void* d_ws, size_t ws_size,
                              hipStream_t stream) {
    const float* x   = (const float*)d_in[0];
    const void*  adj = d_in[1];
    const float* Win = (const float*)d_in[2];
    const float* b_in= (const float*)d_in[3];
    const float* Wq  = (const float*)d_in[4];
    const float* bq  = (const float*)d_in[5];
    const float* Wk  = (const float*)d_in[6];
    const float* bk  = (const float*)d_in[7];
    const float* Wv  = (const float*)d_in[8];
    const float* bv  = (const float*)d_in[9];
    const float* Wo  = (const float*)d_in[10];
    const float* bo  = (const float*)d_in[11];
    const float* Ws  = (const float*)d_in[12];
    const float* bs  = (const float*)d_in[13];
    const float* g1  = (const float*)d_in[14];
    const float* be1 = (const float*)d_in[15];
    const float* g2  = (const float*)d_in[16];
    const float* be2 = (const float*)d_in[17];
    const float* Wf1 = (const float*)d_in[18];
    const float* bf1 = (const float*)d_in[19];
    const float* Wf2 = (const float*)d_in[20];
    const float* bf2 = (const float*)d_in[21];

    char* ws = (char*)d_ws;
    const size_t MB = 1u << 20;
    // live-range-planned layout (~103.5 MB total)
    const size_t OFF_PART = 0;            // 32MB partial O (attn..combine) overlays:
    const size_t OFF_X16  = 0;            //   4MB x bf16          (dead after h-gemm)
    const size_t OFF_H16  = 4 * MB;       //   8MB h bf16          (dead after qkv-gemm)
    const size_t OFF_HN32 = 12 * MB;      //  16MB ln1 f32         (written after combine)
    const size_t OFF_HN16 = 28 * MB;      //   8MB ln1 bf16
    const size_t OFF_FF1  = 4 * MB;       //   8MB (overlays dead H16)
    const size_t OFF_HF32 = 36 * MB;      //  16MB h f32 (h-gemm .. LN1)
    const size_t OFF_QKV  = 52 * MB;      //  24MB fused qkv bf16 (dead after attn)
    const size_t OFF_OP32 = 52 * MB;      //  16MB o-proj f32 (overlays dead QKV)
    const size_t OFF_FF2  = 52 * MB;      //  16MB (overlays dead OP32)
    const size_t OFF_VT   = 76 * MB;      //   8MB (dead after attn)
    const size_t OFF_HFIN = 76 * MB;      //   8MB final hidden (overlays dead VT)
    const size_t OFF_H2   = 84 * MB;      //   8MB attn out bf16
    const size_t OFF_BITS = 92 * MB;      //   8MB adjacency bitmask
    size_t off = 100 * MB;
    const size_t OFF_WINT = off;  off += 262144;    // Win^T  bf16 512x256
    const size_t OFF_QKVT = off;  off += 1572864;   // [Wq|Wk|Wv]^T bf16 1536x512
    const size_t OFF_WOT  = off;  off += 524288;
    const size_t OFF_WF1T = off;  off += 524288;
    const size_t OFF_WF2T = off;  off += 524288;
    const size_t OFF_BQKV = off;  off += 8192;      // 1536 f32
    const size_t OFF_MODE = off;  off += 4096;
    const size_t OFF_MPART= off;  off += 131072;    // 4x8192 f32
    const size_t OFF_LPART= off;  off += 131072;

    u16* pX16   = (u16*)(ws + OFF_X16);
    u16* pH16   = (u16*)(ws + OFF_H16);
    float* pHN32= (float*)(ws + OFF_HN32);
    u16* pHN16  = (u16*)(ws + OFF_HN16);
    u16* pFF1   = (u16*)(ws + OFF_FF1);
    float* pHF32= (float*)(ws + OFF_HF32);
    u16* pQKV   = (u16*)(ws + OFF_QKV);
    float* pOP32= (float*)(ws + OFF_OP32);
    float* pFF2 = (float*)(ws + OFF_FF2);
    u16* pVT    = (u16*)(ws + OFF_VT);
    u16* pHFIN  = (u16*)(ws + OFF_HFIN);
    u16* pH2    = (u16*)(ws + OFF_H2);
    u32* pBits  = (u32*)(ws + OFF_BITS);
    u16* pPart  = (u16*)(ws + OFF_PART);
    u16* pWinT  = (u16*)(ws + OFF_WINT);
    u16* pQKVT  = (u16*)(ws + OFF_QKVT);
    u16* pWoT   = (u16*)(ws + OFF_WOT);
    u16* pWf1T  = (u16*)(ws + OFF_WF1T);
    u16* pWf2T  = (u16*)(ws + OFF_WF2T);
    float* pBqkv= (float*)(ws + OFF_BQKV);
    int* pMode  = (int*)(ws + OFF_MODE);
    float* pMp  = (float*)(ws + OFF_MPART);
    float* pLp  = (float*)(ws + OFF_LPART);

    // adjacency bitmask
    sniff_adj<<<1, 64, 0, stream>>>((const u32*)adj, pMode);
    build_bits<<<NROW, 256, 0, stream>>>(adj, pMode, pBits);

    // conversions
    convert_f32_bf16<<<(NROW * DIN) / 256, 256, 0, stream>>>(x, pX16, NROW * DIN);
    convert_wt<<<(DIN * HID + 255) / 256, 256, 0, stream>>>(Win, pWinT, DIN, HID);
    convert_wt<<<(HID * HID + 255) / 256, 256, 0, stream>>>(Wq, pQKVT, HID, HID);
    convert_wt<<<(HID * HID + 255) / 256, 256, 0, stream>>>(Wk, pQKVT + 512 * 512, HID, HID);
    convert_wt<<<(HID * HID + 255) / 256, 256, 0, stream>>>(Wv, pQKVT + 2 * 512 * 512, HID, HID);
    convert_wt<<<(HID * HID + 255) / 256, 256, 0, stream>>>(Wo, pWoT, HID, HID);
    convert_wt<<<(HID * HID + 255) / 256, 256, 0, stream>>>(Wf1, pWf1T, HID, HID);
    convert_wt<<<(HID * HID + 255) / 256, 256, 0, stream>>>(Wf2, pWf2T, HID, HID);
    concat_bias<<<6, 256, 0, stream>>>(bq, bk, bv, pBqkv);

    // h = x @ Win + b_in (f32 + bf16)
    gemm_tn<64, 32><<<dim3(8, 64), 256, 0, stream>>>(pX16, DIN, pWinT, b_in,
                                                     pHF32, pH16, HID, 0, DIN);
    // qkv = h @ [Wq|Wk|Wv] (bf16, fused, ldo=1536)
    gemm_tn<64, 64><<<dim3(12, 64), 256, 0, stream>>>(pH16, HID, pQKVT, pBqkv,
                                                      nullptr, pQKV, LDQ, 0, HID);
    // vt
    transpose_v<<<dim3(HID / 64, NROW / 64), 256, 0, stream>>>(pQKV + 1024, LDQ, pVT);
    // attention (split-KV) + combine
    attn_kernel<<<64 * NSPLIT, 512, 0, stream>>>(pQKV, pVT, pBits, pPart, pMp, pLp);
    attn_combine<<<NROW * HID / (256 * 8), 256, 0, stream>>>(pPart, pMp, pLp, pH2);
    // o-proj (f32)
    gemm_tn<64, 32><<<dim3(8, 64), 256, 0, stream>>>(pH2, HID, pWoT, bo,
                                                     pOP32, nullptr, HID, 0, HID);
    // LN1
    ln_add<<<NROW, 256, 0, stream>>>(pHF32, pOP32, g1, be1, pHN32, pHN16);
    // ff1 = relu(hn @ Wf1 + bf1)
    gemm_tn<64, 32><<<dim3(8, 64), 256, 0, stream>>>(pHN16, HID, pWf1T, bf1,
                                                     nullptr, pFF1, HID, 1, HID);
    // ff2
    gemm_tn<64, 32><<<dim3(8, 64), 256, 0, stream>>>(pFF1, HID, pWf2T, bf2,
                                                     pFF2, nullptr, HID, 0, HID);
    // LN2 -> bf16
    ln_add<<<NROW, 256, 0, stream>>>(pHN32, pFF2, g2, be2, nullptr, pHFIN);
    // logits
    logits_k<<<NROW / 4, 256, 0, stream>>>(pHFIN, Ws, bs, (float*)d_out);
}

// Round 3
// 862.484 us; speedup vs baseline: 4.5770x; 1.7494x over previous
//
#include <hip/hip_runtime.h>

typedef unsigned int u32;
typedef unsigned short u16;
typedef unsigned char u8;

typedef __bf16 bf16_t;
typedef bf16_t bf16x8 __attribute__((ext_vector_type(8)));
typedef float f32x4 __attribute__((ext_vector_type(4)));

#define NROW 8192
#define HID 512
#define DIN 256
#define LDQ 1536   // row stride of fused qkv buffer
#define NSPLIT 4
#define KVCH (NROW / NSPLIT)   // 2048
#define KVB 32                 // kv tile

__device__ __forceinline__ u16 f2b(float f) {
    u32 u = __float_as_uint(f);
    u32 r = (u + 0x7fffu + ((u >> 16) & 1u)) >> 16;
    return (u16)r;
}
__device__ __forceinline__ float b2f(u16 h) {
    return __uint_as_float(((u32)h) << 16);
}
__device__ __forceinline__ f32x4 zero4() {
    f32x4 z = {0.f, 0.f, 0.f, 0.f};
    return z;
}
__device__ __forceinline__ void gll16(const void* g, void* l) {
    __builtin_amdgcn_global_load_lds(
        (const __attribute__((address_space(1))) unsigned int*)g,
        (__attribute__((address_space(3))) unsigned int*)l, 16, 0, 0);
}

// ---------------- adj dtype sniffing ----------------
__global__ void sniff_adj(const u32* __restrict__ adj, int* __restrict__ mode) {
    if (threadIdx.x != 0) return;
    int all01 = 1, allf32 = 1, allbf = 1;
    for (int i = 0; i < 1024; i++) {
        u32 w = adj[i];
        if (w > 1u) all01 = 0;
        if (w != 0u && w != 0x3f800000u) allf32 = 0;
    }
    const u16* h = (const u16*)adj;
    for (int i = 0; i < 2048; i++) {
        u16 v = h[i];
        if (v != 0 && v != 0x3f80u) allbf = 0;
    }
    mode[0] = all01 ? 0 : (allf32 ? 1 : (allbf ? 2 : 3));
}

__global__ __launch_bounds__(256) void build_bits(const void* __restrict__ adj,
                                                  const int* __restrict__ mode,
                                                  u32* __restrict__ bits) {
    int row = blockIdx.x;
    int t = threadIdx.x;
    int lane = t & 63, wv = t >> 6;
    int md = *mode;
    for (int c0 = 0; c0 < NROW; c0 += 256) {
        int c = c0 + t;
        size_t idx = (size_t)row * NROW + c;
        bool nz;
        if (md == 0)      nz = ((const u32*)adj)[idx] != 0u;
        else if (md == 1) nz = ((const float*)adj)[idx] != 0.f;
        else if (md == 2) nz = ((const u16*)adj)[idx] != 0;
        else              nz = ((const u8*)adj)[idx] != 0;
        unsigned long long bm = __ballot(nz);
        if (lane == 0) {
            int w = row * 256 + (c0 >> 5) + wv * 2;
            bits[w] = (u32)bm;
            bits[w + 1] = (u32)(bm >> 32);
        }
    }
}

// ---------------- conversions ----------------
__global__ __launch_bounds__(256) void convert_f32_bf16(const float* __restrict__ in,
                                                        u16* __restrict__ out, int n) {
    int i = blockIdx.x * 256 + threadIdx.x;
    if (i < n) out[i] = f2b(in[i]);
}

// W [R][C] f32 -> Wt [C][R] bf16 (tiled transpose, coalesced both sides)
__global__ __launch_bounds__(256) void transpose_wt(const float* __restrict__ W,
                                                    u16* __restrict__ out, int R, int C) {
    __shared__ u16 tile[64][65];
    int c0 = blockIdx.x * 64, r0 = blockIdx.y * 64;
    int t = threadIdx.x;
#pragma unroll
    for (int i = 0; i < 16; i++) {
        int idx = t + i * 256;
        int rr = idx >> 6, cc = idx & 63;
        tile[rr][cc] = f2b(W[(size_t)(r0 + rr) * C + c0 + cc]);
    }
    __syncthreads();
#pragma unroll
    for (int i = 0; i < 16; i++) {
        int idx = t + i * 256;
        int rr = idx >> 6, cc = idx & 63;
        out[(size_t)(c0 + rr) * R + r0 + cc] = tile[cc][rr];
    }
}

__global__ void concat_bias(const float* __restrict__ bq, const float* __restrict__ bk,
                            const float* __restrict__ bv, float* __restrict__ out) {
    int i = blockIdx.x * 256 + threadIdx.x;
    if (i >= 1536) return;
    out[i] = i < 512 ? bq[i] : (i < 1024 ? bk[i - 512] : bv[i - 1024]);
}

// V (rows of QKV, stride ldv) -> tiled VT: out[(kv>>5)*(HID*32) + col*32 + (kv&31)]
__global__ __launch_bounds__(256) void transpose_v_tiled(const u16* __restrict__ in, int ldv,
                                                         u16* __restrict__ out) {
    __shared__ u16 tile[64][65];
    int c0 = blockIdx.x * 64;   // col block (HID)
    int r0 = blockIdx.y * 64;   // kv block (NROW)
    int t = threadIdx.x;
#pragma unroll
    for (int i = 0; i < 16; i++) {
        int idx = t + i * 256;
        int rr = idx >> 6, cc = idx & 63;
        tile[rr][cc] = in[(size_t)(r0 + rr) * ldv + c0 + cc];
    }
    __syncthreads();
#pragma unroll
    for (int i = 0; i < 16; i++) {
        int idx = t + i * 256;
        int rr = idx >> 6, cc = idx & 63;
        int kv = r0 + cc, col = c0 + rr;
        out[(size_t)(kv >> 5) * (HID * 32) + col * 32 + (kv & 31)] = tile[cc][rr];
    }
}

// ---------------- GEMM 128x128, BK=64, LDS double-buffered ----------------
// C[M,ldo] = A[M,K](lda) @ Bt[N,K]^T + bias; optional relu, dual f32/bf16 out
__global__ __launch_bounds__(256, 2) void gemm128(const u16* __restrict__ A, int lda,
                                                  const u16* __restrict__ Bt,
                                                  const float* __restrict__ bias,
                                                  float* __restrict__ outF,
                                                  u16* __restrict__ outH, int ldo,
                                                  int relu, int K) {
    __shared__ u16 Ald[2][8192];
    __shared__ u16 Bld[2][8192];
    int lane = threadIdx.x & 63, wave = threadIdx.x >> 6;
    int l15 = lane & 15, lg = lane >> 4;
    int wr = wave >> 1, wc = wave & 1;
    int row0 = blockIdx.y * 128, col0 = blockIdx.x * 128;

    // stage one 128x64 tile of A and Bt into buf (source-swizzled: chunk c ^= row&7)
    auto stage = [&](int buf, int kk) {
#pragma unroll
        for (int i = 0; i < 4; i++) {
            int seg = wave * 4 + i;             // 0..15 (1KB segments)
            int row = seg * 8 + (lane >> 3);
            int c = lane & 7;
            int csw = c ^ (row & 7);
            gll16(A + (size_t)(row0 + row) * lda + kk + csw * 8,
                  &Ald[buf][seg * 512 + lane * 8]);
            gll16(Bt + (size_t)(col0 + row) * K + kk + csw * 8,
                  &Bld[buf][seg * 512 + lane * 8]);
        }
    };

    f32x4 acc[4][4];
#pragma unroll
    for (int i = 0; i < 4; i++)
#pragma unroll
        for (int j = 0; j < 4; j++) acc[i][j] = zero4();

    stage(0, 0);
    asm volatile("s_waitcnt vmcnt(0)" ::: "memory");
    __syncthreads();

    int nk = K >> 6;
    for (int kt = 0; kt < nk; kt++) {
        int buf = kt & 1;
        if (kt + 1 < nk) stage(buf ^ 1, (kt + 1) * 64);
#pragma unroll
        for (int ks = 0; ks < 2; ks++) {
            bf16x8 af[4], bfr[4];
#pragma unroll
            for (int i = 0; i < 4; i++) {
                int row = wr * 64 + i * 16 + l15;
                af[i] = *(const bf16x8*)&Ald[buf][row * 64 + (((ks * 4 + lg) ^ (row & 7)) * 8)];
            }
#pragma unroll
            for (int j = 0; j < 4; j++) {
                int row = wc * 64 + j * 16 + l15;
                bfr[j] = *(const bf16x8*)&Bld[buf][row * 64 + (((ks * 4 + lg) ^ (row & 7)) * 8)];
            }
            __builtin_amdgcn_s_setprio(1);
#pragma unroll
            for (int i = 0; i < 4; i++)
#pragma unroll
                for (int j = 0; j < 4; j++)
                    acc[i][j] = __builtin_amdgcn_mfma_f32_16x16x32_bf16(af[i], bfr[j],
                                                                       acc[i][j], 0, 0, 0);
            __builtin_amdgcn_s_setprio(0);
        }
        asm volatile("s_waitcnt vmcnt(0)" ::: "memory");
        __syncthreads();
    }
#pragma unroll
    for (int j = 0; j < 4; j++) {
        int col = col0 + wc * 64 + j * 16 + l15;
        float bv = bias[col];
#pragma unroll
        for (int i = 0; i < 4; i++) {
#pragma unroll
            for (int r = 0; r < 4; r++) {
                int row = row0 + wr * 64 + i * 16 + lg * 4 + r;
                float v = acc[i][j][r] + bv;
                if (relu) v = fmaxf(v, 0.f);
                size_t o = (size_t)row * ldo + col;
                if (outF) outF[o] = v;
                if (outH) outH[o] = f2b(v);
            }
        }
    }
}

// ---------------- split-KV flash attention v3 ----------------
// 256 blocks = 64 qb x 4 splits; 8 waves x 16 q rows; KVB=32.
// K LDS-staged (double-buffered, 16 panels of [32kv][32k]); V from tiled-VT
// global (L1/L2); Q resident in registers.
__global__ __launch_bounds__(512, 2) void attn_kernel(const u16* __restrict__ QKV,
                                                      const u16* __restrict__ VTt,
                                                      const u32* __restrict__ bits,
                                                      u16* __restrict__ Opart,
                                                      float* __restrict__ Mpart,
                                                      float* __restrict__ Lpart) {
    extern __shared__ char smem[];
    u16* Klds = (u16*)smem;                               // 2 x 32KB
    int lane = threadIdx.x & 63, wave = threadIdx.x >> 6;
    u16* myp = (u16*)(smem + 65536) + wave * 512;         // per-wave 16x32 P
    int l15 = lane & 15, lg = lane >> 4;
    int s = blockIdx.x & 3;
    int qb = blockIdx.x >> 2;
    int qbase = qb * 128 + wave * 16;
    const u16* Kg = QKV + 512;

    // Q preload: 16 A-frags (64 VGPR)
    bf16x8 qf[16];
    {
        const u16* qp = QKV + (size_t)(qbase + l15) * LDQ + lg * 8;
#pragma unroll
        for (int ks = 0; ks < 16; ks++) qf[ks] = *(const bf16x8*)(qp + ks * 32);
    }

    f32x4 acc[32];
#pragma unroll
    for (int i = 0; i < 32; i++) acc[i] = zero4();
    float m[4] = {-1e30f, -1e30f, -1e30f, -1e30f};
    float lsum[4] = {0.f, 0.f, 0.f, 0.f};
    const float scale = 0.04419417382415922f;  // 1/sqrt(512)
    int kvbeg = s * KVCH;

    auto STAGE = [&](int buf, int kv0) {
#pragma unroll
        for (int i = 0; i < 4; i++) {
            int seg = wave * 4 + i;            // 0..31 (1KB segments)
            int ks = seg >> 1, half = seg & 1;
            int kv = half * 16 + (lane >> 2), c = lane & 3;
            gll16(Kg + (size_t)(kv0 + kv) * LDQ + ks * 32 + c * 8,
                  Klds + buf * 16384 + seg * 512 + lane * 8);
        }
    };

    STAGE(0, kvbeg);
    asm volatile("s_waitcnt vmcnt(0)" ::: "memory");
    __syncthreads();

    for (int t = 0; t < KVCH / KVB; ++t) {
        int kv0 = kvbeg + t * KVB;
        int buf = t & 1;
        if (t + 1 < KVCH / KVB) STAGE(buf ^ 1, kv0 + KVB);
        const u16* kb = Klds + buf * 16384;

        // ---- S = Q(16x512) @ K^T(512x32) ----
        f32x4 sf[2];
        sf[0] = zero4(); sf[1] = zero4();
        __builtin_amdgcn_s_setprio(1);
#pragma unroll
        for (int ks = 0; ks < 16; ks++) {
            bf16x8 b0 = *(const bf16x8*)(kb + ks * 1024 + l15 * 32 + lg * 8);
            bf16x8 b1 = *(const bf16x8*)(kb + ks * 1024 + (16 + l15) * 32 + lg * 8);
            sf[0] = __builtin_amdgcn_mfma_f32_16x16x32_bf16(qf[ks], b0, sf[0], 0, 0, 0);
            sf[1] = __builtin_amdgcn_mfma_f32_16x16x32_bf16(qf[ks], b1, sf[1], 0, 0, 0);
        }
        __builtin_amdgcn_s_setprio(0);

        // ---- mask + online softmax (defer-max THR=8) ----
        u32 w0[4];
#pragma unroll
        for (int r = 0; r < 4; r++)
            w0[r] = bits[(size_t)(qbase + lg * 4 + r) * 256 + (kv0 >> 5)];
        float pvv[2][4];
        float mx[4] = {-1e30f, -1e30f, -1e30f, -1e30f};
#pragma unroll
        for (int f = 0; f < 2; f++) {
            int c = f * 16 + l15;
#pragma unroll
            for (int r = 0; r < 4; r++) {
                bool bit = (w0[r] >> c) & 1u;
                float sv = bit ? sf[f][r] * scale : -1e30f;
                pvv[f][r] = sv;
                mx[r] = fmaxf(mx[r], sv);
            }
        }
#pragma unroll
        for (int r = 0; r < 4; r++) {
#pragma unroll
            for (int off = 8; off; off >>= 1)
                mx[r] = fmaxf(mx[r], __shfl_xor(mx[r], off, 64));
        }
        bool need = false;
#pragma unroll
        for (int r = 0; r < 4; r++) need |= (mx[r] > m[r] + 8.0f);
        if (__any(need ? 1 : 0)) {
            float csc[4];
#pragma unroll
            for (int r = 0; r < 4; r++) {
                float mn = fmaxf(m[r], mx[r]);
                csc[r] = __expf(m[r] - mn);
                m[r] = mn;
                lsum[r] *= csc[r];
            }
#pragma unroll
            for (int i = 0; i < 32; i++) {
                f32x4 a = acc[i];
                a[0] *= csc[0]; a[1] *= csc[1]; a[2] *= csc[2]; a[3] *= csc[3];
                acc[i] = a;
            }
        }
#pragma unroll
        for (int f = 0; f < 2; f++)
#pragma unroll
            for (int r = 0; r < 4; r++)
                pvv[f][r] = (pvv[f][r] < -1e29f) ? 0.f : __expf(pvv[f][r] - m[r]);
#pragma unroll
        for (int r = 0; r < 4; r++) {
            float rs = pvv[0][r] + pvv[1][r];
#pragma unroll
            for (int off = 8; off; off >>= 1) rs += __shfl_xor(rs, off, 64);
            lsum[r] += rs;
        }

        // ---- P (D-layout) -> per-wave LDS -> A-frag ----
#pragma unroll
        for (int f = 0; f < 2; f++)
#pragma unroll
            for (int r = 0; r < 4; r++)
                myp[(lg * 4 + r) * 32 + f * 16 + l15] = f2b(pvv[f][r]);
        asm volatile("s_waitcnt lgkmcnt(0)" ::: "memory");
        __builtin_amdgcn_sched_barrier(0);
        bf16x8 pa = *(const bf16x8*)(myp + l15 * 32 + lg * 8);

        // ---- O += P(16x32) @ V(32x512), V from tiled-VT, prefetch depth 2 ----
        const u16* vb = VTt + (size_t)(kv0 >> 5) * (HID * 32);
        bf16x8 v_c = *(const bf16x8*)(vb + (size_t)l15 * 32 + lg * 8);
        bf16x8 v_n = *(const bf16x8*)(vb + (size_t)(16 + l15) * 32 + lg * 8);
        __builtin_amdgcn_s_setprio(1);
#pragma unroll
        for (int cf = 0; cf < 32; ++cf) {
            bf16x8 v_f = v_c;
            if (cf + 2 < 32)
                v_f = *(const bf16x8*)(vb + (size_t)((cf + 2) * 16 + l15) * 32 + lg * 8);
            acc[cf] = __builtin_amdgcn_mfma_f32_16x16x32_bf16(pa, v_c, acc[cf], 0, 0, 0);
            v_c = v_n; v_n = v_f;
        }
        __builtin_amdgcn_s_setprio(0);

        asm volatile("s_waitcnt vmcnt(0)" ::: "memory");
        __syncthreads();
    }

    // ---- write partials (unnormalized, with per-row m, l) ----
    if (l15 == 0) {
#pragma unroll
        for (int r = 0; r < 4; r++) {
            size_t o = (size_t)s * NROW + qbase + lg * 4 + r;
            Mpart[o] = m[r];
            Lpart[o] = lsum[r];
        }
    }
#pragma unroll
    for (int cf = 0; cf < 32; cf++) {
        int col = cf * 16 + l15;
#pragma unroll
        for (int r = 0; r < 4; r++) {
            size_t row = (size_t)s * NROW + qbase + lg * 4 + r;
            Opart[row * HID + col] = f2b(acc[cf][r]);
        }
    }
}

// combine 4 split partials -> O16
__global__ __launch_bounds__(256) void attn_combine(const u16* __restrict__ Opart,
                                                    const float* __restrict__ Mpart,
                                                    const float* __restrict__ Lpart,
                                                    u16* __restrict__ O16) {
    int idx = blockIdx.x * 256 + threadIdx.x;
    int row = idx >> 6;
    int c8 = (idx & 63) << 3;
    float ms[NSPLIT], M = -1e30f;
#pragma unroll
    for (int s = 0; s < NSPLIT; s++) {
        ms[s] = Mpart[(size_t)s * NROW + row];
        M = fmaxf(M, ms[s]);
    }
    float w[NSPLIT], L = 0.f;
#pragma unroll
    for (int s = 0; s < NSPLIT; s++) {
        w[s] = __expf(ms[s] - M);
        L += Lpart[(size_t)s * NROW + row] * w[s];
    }
    float inv = 1.f / L;
    float o[8];
#pragma unroll
    for (int j = 0; j < 8; j++) o[j] = 0.f;
#pragma unroll
    for (int s = 0; s < NSPLIT; s++) {
        bf16x8 p = *(const bf16x8*)(Opart + ((size_t)s * NROW + row) * HID + c8);
#pragma unroll
        for (int j = 0; j < 8; j++) o[j] += (float)p[j] * w[s];
    }
    bf16x8 res;
#pragma unroll
    for (int j = 0; j < 8; j++) {
        u16 b = f2b(o[j] * inv);
        res[j] = *(bf16_t*)&b;
    }
    *(bf16x8*)(O16 + (size_t)row * HID + c8) = res;
}

// ---------------- layernorm(a+b) ----------------
__global__ __launch_bounds__(256) void ln_add(const float* __restrict__ a,
                                              const float* __restrict__ b,
                                              const float* __restrict__ g,
                                              const float* __restrict__ be,
                                              float* __restrict__ outF,
                                              u16* __restrict__ outH) {
    int row = blockIdx.x, t = threadIdx.x;
    const float* ar = a + (size_t)row * HID;
    const float* br = b + (size_t)row * HID;
    float x0 = ar[t] + br[t];
    float x1 = ar[t + 256] + br[t + 256];
    float s = x0 + x1, s2 = x0 * x0 + x1 * x1;
#pragma unroll
    for (int off = 32; off; off >>= 1) {
        s += __shfl_xor(s, off, 64);
        s2 += __shfl_xor(s2, off, 64);
    }
    __shared__ float ls[4], ls2[4];
    int wv = t >> 6, ln = t & 63;
    if (ln == 0) { ls[wv] = s; ls2[wv] = s2; }
    __syncthreads();
    float S = ls[0] + ls[1] + ls[2] + ls[3];
    float S2 = ls2[0] + ls2[1] + ls2[2] + ls2[3];
    float mu = S * (1.f / 512.f);
    float var = S2 * (1.f / 512.f) - mu * mu;
    float inv = rsqrtf(var + 1e-5f);
    float y0 = (x0 - mu) * inv * g[t] + be[t];
    float y1 = (x1 - mu) * inv * g[t + 256] + be[t + 256];
    size_t o = (size_t)row * HID + t;
    if (outF) { outF[o] = y0; outF[o + 256] = y1; }
    if (outH) { outH[o] = f2b(y0); outH[o + 256] = f2b(y1); }
}

// ---------------- logits ----------------
__global__ __launch_bounds__(256) void logits_k(const u16* __restrict__ hfin,
                                                const float* __restrict__ Ws,
                                                const float* __restrict__ bs,
                                                float* __restrict__ out) {
    int row = blockIdx.x * 4 + (threadIdx.x >> 6);
    int lane = threadIdx.x & 63;
    const u16* hp = hfin + (size_t)row * HID + lane * 8;
    float sum = 0.f;
#pragma unroll
    for (int j = 0; j < 8; j++) sum += b2f(hp[j]) * Ws[lane * 8 + j];
#pragma unroll
    for (int off = 32; off; off >>= 1) sum += __shfl_xor(sum, off, 64);
    if (lane == 0) out[row] = sum + bs[0];
}

// ---------------- host launcher ----------------
extern "C" void kernel_launch(void* const* d_in, const int* in_sizes, int n_in,
                              void* d_out, int out_size, void* d_ws, size_t ws_size,
                              hipStream_t stream) {
    const float* x   = (const float*)d_in[0];
    const void*  adj = d_in[1];
    const float* Win = (const float*)d_in[2];
    const float* b_in= (const float*)d_in[3];
    const float* Wq  = (const float*)d_in[4];
    const float* bq  = (const float*)d_in[5];
    const float* Wk  = (const float*)d_in[6];
    const float* bk  = (const float*)d_in[7];
    const float* Wv  = (const float*)d_in[8];
    const float* bv  = (const float*)d_in[9];
    const float* Wo  = (const float*)d_in[10];
    const float* bo  = (const float*)d_in[11];
    const float* Ws  = (const float*)d_in[12];
    const float* bs  = (const float*)d_in[13];
    const float* g1  = (const float*)d_in[14];
    const float* be1 = (const float*)d_in[15];
    const float* g2  = (const float*)d_in[16];
    const float* be2 = (const float*)d_in[17];
    const float* Wf1 = (const float*)d_in[18];
    const float* bf1 = (const float*)d_in[19];
    const float* Wf2 = (const float*)d_in[20];
    const float* bf2 = (const float*)d_in[21];

    char* ws = (char*)d_ws;
    const size_t MB = 1u << 20;
    const size_t OFF_PART = 0;            // 32MB partial O (attn..combine) overlays:
    const size_t OFF_X16  = 0;            //   4MB x bf16   (dead after h-gemm)
    const size_t OFF_H16  = 4 * MB;       //   8MB h bf16   (dead after qkv-gemm)
    const size_t OFF_HN32 = 12 * MB;      //  16MB ln1 f32  (written after combine)
    const size_t OFF_HN16 = 28 * MB;      //   8MB ln1 bf16
    const size_t OFF_FF1  = 4 * MB;       //   8MB (overlays dead H16)
    const size_t OFF_HF32 = 36 * MB;      //  16MB h f32 (h-gemm .. LN1)
    const size_t OFF_QKV  = 52 * MB;      //  24MB fused qkv bf16 (dead after attn)
    const size_t OFF_OP32 = 52 * MB;      //  16MB o-proj f32 (overlays dead QKV)
    const size_t OFF_FF2  = 52 * MB;      //  16MB (overlays dead OP32)
    const size_t OFF_VT   = 76 * MB;      //   8MB tiled VT (dead after attn)
    const size_t OFF_HFIN = 76 * MB;      //   8MB final hidden (overlays dead VT)
    const size_t OFF_H2   = 84 * MB;      //   8MB attn out bf16
    const size_t OFF_BITS = 92 * MB;      //   8MB adjacency bitmask
    size_t off = 100 * MB;
    const size_t OFF_WINT = off;  off += 262144;
    const size_t OFF_QKVT = off;  off += 1572864;
    const size_t OFF_WOT  = off;  off += 524288;
    const size_t OFF_WF1T = off;  off += 524288;
    const size_t OFF_WF2T = off;  off += 524288;
    const size_t OFF_BQKV = off;  off += 8192;
    const size_t OFF_MODE = off;  off += 4096;
    const size_t OFF_MPART= off;  off += 131072;
    const size_t OFF_LPART= off;  off += 131072;

    u16* pX16   = (u16*)(ws + OFF_X16);
    u16* pH16   = (u16*)(ws + OFF_H16);
    float* pHN32= (float*)(ws + OFF_HN32);
    u16* pHN16  = (u16*)(ws + OFF_HN16);
    u16* pFF1   = (u16*)(ws + OFF_FF1);
    float* pHF32= (float*)(ws + OFF_HF32);
    u16* pQKV   = (u16*)(ws + OFF_QKV);
    float* pOP32= (float*)(ws + OFF_OP32);
    float* pFF2 = (float*)(ws + OFF_FF2);
    u16* pVT    = (u16*)(ws + OFF_VT);
    u16* pHFIN  = (u16*)(ws + OFF_HFIN);
    u16* pH2    = (u16*)(ws + OFF_H2);
    u32* pBits  = (u32*)(ws + OFF_BITS);
    u16* pPart  = (u16*)(ws + OFF_PART);
    u16* pWinT  = (u16*)(ws + OFF_WINT);
    u16* pQKVT  = (u16*)(ws + OFF_QKVT);
    u16* pWoT   = (u16*)(ws + OFF_WOT);
    u16* pWf1T  = (u16*)(ws + OFF_WF1T);
    u16* pWf2T  = (u16*)(ws + OFF_WF2T);
    float* pBqkv= (float*)(ws + OFF_BQKV);
    int* pMode  = (int*)(ws + OFF_MODE);
    float* pMp  = (float*)(ws + OFF_MPART);
    float* pLp  = (float*)(ws + OFF_LPART);

    // adjacency bitmask
    sniff_adj<<<1, 64, 0, stream>>>((const u32*)adj, pMode);
    build_bits<<<NROW, 256, 0, stream>>>(adj, pMode, pBits);

    // conversions (tiled transposes, coalesced)
    convert_f32_bf16<<<(NROW * DIN) / 256, 256, 0, stream>>>(x, pX16, NROW * DIN);
    transpose_wt<<<dim3(8, 4), 256, 0, stream>>>(Win, pWinT, DIN, HID);
    transpose_wt<<<dim3(8, 8), 256, 0, stream>>>(Wq, pQKVT, HID, HID);
    transpose_wt<<<dim3(8, 8), 256, 0, stream>>>(Wk, pQKVT + 512 * 512, HID, HID);
    transpose_wt<<<dim3(8, 8), 256, 0, stream>>>(Wv, pQKVT + 2 * 512 * 512, HID, HID);
    transpose_wt<<<dim3(8, 8), 256, 0, stream>>>(Wo, pWoT, HID, HID);
    transpose_wt<<<dim3(8, 8), 256, 0, stream>>>(Wf1, pWf1T, HID, HID);
    transpose_wt<<<dim3(8, 8), 256, 0, stream>>>(Wf2, pWf2T, HID, HID);
    concat_bias<<<6, 256, 0, stream>>>(bq, bk, bv, pBqkv);

    // h = x @ Win + b_in (f32 + bf16)
    gemm128<<<dim3(4, 64), 256, 0, stream>>>(pX16, DIN, pWinT, b_in,
                                             pHF32, pH16, HID, 0, DIN);
    // qkv = h @ [Wq|Wk|Wv] (bf16, fused, ldo=1536)
    gemm128<<<dim3(12, 64), 256, 0, stream>>>(pH16, HID, pQKVT, pBqkv,
                                              nullptr, pQKV, LDQ, 0, HID);
    // tiled vt
    transpose_v_tiled<<<dim3(HID / 64, NROW / 64), 256, 0, stream>>>(pQKV + 1024, LDQ, pVT);
    // attention (split-KV) + combine
    attn_kernel<<<64 * NSPLIT, 512, 73728, stream>>>(pQKV, pVT, pBits, pPart, pMp, pLp);
    attn_combine<<<NROW * HID / (256 * 8), 256, 0, stream>>>(pPart, pMp, pLp, pH2);
    // o-proj (f32)
    gemm128<<<dim3(4, 64), 256, 0, stream>>>(pH2, HID, pWoT, bo,
                                             pOP32, nullptr, HID, 0, HID);
    // LN1
    ln_add<<<NROW, 256, 0, stream>>>(pHF32, pOP32, g1, be1, pHN32, pHN16);
    // ff1 = relu(hn @ Wf1 + bf1)
    gemm128<<<dim3(4, 64), 256, 0, stream>>>(pHN16, HID, pWf1T, bf1,
                                             nullptr, pFF1, HID, 1, HID);
    // ff2
    gemm128<<<dim3(4, 64), 256, 0, stream>>>(pFF1, HID, pWf2T, bf2,
                                             pFF2, nullptr, HID, 0, HID);
    // LN2 -> bf16
    ln_add<<<NROW, 256, 0, stream>>>(pHN32, pFF2, g2, be2, nullptr, pHFIN);
    // logits
    logits_k<<<NROW / 4, 256, 0, stream>>>(pHFIN, Ws, bs, (float*)d_out);
}

// Round 4
// 706.502 us; speedup vs baseline: 5.5875x; 1.2208x over previous
//
#include <hip/hip_runtime.h>

typedef unsigned int u32;
typedef unsigned short u16;
typedef unsigned char u8;

typedef __bf16 bf16_t;
typedef bf16_t bf16x8 __attribute__((ext_vector_type(8)));
typedef float f32x4 __attribute__((ext_vector_type(4)));

#define NROW 8192
#define HID 512
#define DIN 256
#define LDQ 1536   // row stride of fused qkv buffer
#define NSPLIT 4
#define KVCH (NROW / NSPLIT)   // 2048
#define KVB 32                 // kv tile

__device__ __forceinline__ u16 f2b(float f) {
    u32 u = __float_as_uint(f);
    u32 r = (u + 0x7fffu + ((u >> 16) & 1u)) >> 16;
    return (u16)r;
}
__device__ __forceinline__ float b2f(u16 h) {
    return __uint_as_float(((u32)h) << 16);
}
__device__ __forceinline__ f32x4 zero4() {
    f32x4 z = {0.f, 0.f, 0.f, 0.f};
    return z;
}
__device__ __forceinline__ void gll16(const void* g, void* l) {
    __builtin_amdgcn_global_load_lds(
        (const __attribute__((address_space(1))) unsigned int*)g,
        (__attribute__((address_space(3))) unsigned int*)l, 16, 0, 0);
}

// ---------------- adj dtype sniffing (wave-parallel) ----------------
__global__ void sniff_adj(const u32* __restrict__ adj, int* __restrict__ mode) {
    int lane = threadIdx.x & 63;
    int all01 = 1, allf32 = 1, allbf = 1;
    for (int i = lane; i < 1024; i += 64) {
        u32 w = adj[i];
        if (w > 1u) all01 = 0;
        if (w != 0u && w != 0x3f800000u) allf32 = 0;
    }
    const u16* h = (const u16*)adj;
    for (int i = lane; i < 2048; i += 64) {
        u16 v = h[i];
        if (v != 0 && v != 0x3f80u) allbf = 0;
    }
    all01 = __all(all01);
    allf32 = __all(allf32);
    allbf = __all(allbf);
    if (lane == 0) mode[0] = all01 ? 0 : (allf32 ? 1 : (allbf ? 2 : 3));
}

__global__ __launch_bounds__(256) void build_bits(const void* __restrict__ adj,
                                                  const int* __restrict__ mode,
                                                  u32* __restrict__ bits) {
    int row = blockIdx.x;
    int t = threadIdx.x;
    int lane = t & 63, wv = t >> 6;
    int md = *mode;
    for (int c0 = 0; c0 < NROW; c0 += 256) {
        int c = c0 + t;
        size_t idx = (size_t)row * NROW + c;
        bool nz;
        if (md == 0)      nz = ((const u32*)adj)[idx] != 0u;
        else if (md == 1) nz = ((const float*)adj)[idx] != 0.f;
        else if (md == 2) nz = ((const u16*)adj)[idx] != 0;
        else              nz = ((const u8*)adj)[idx] != 0;
        unsigned long long bm = __ballot(nz);
        if (lane == 0) {
            int w = row * 256 + (c0 >> 5) + wv * 2;
            bits[w] = (u32)bm;
            bits[w + 1] = (u32)(bm >> 32);
        }
    }
}

// ---------------- conversions ----------------
__global__ __launch_bounds__(256) void convert_f32_bf16(const float* __restrict__ in,
                                                        u16* __restrict__ out, int n) {
    int i = blockIdx.x * 256 + threadIdx.x;
    if (i < n) out[i] = f2b(in[i]);
}

// W [R][C] f32 -> Wt [C][R] bf16 (tiled transpose, coalesced both sides)
__global__ __launch_bounds__(256) void transpose_wt(const float* __restrict__ W,
                                                    u16* __restrict__ out, int R, int C) {
    __shared__ u16 tile[64][65];
    int c0 = blockIdx.x * 64, r0 = blockIdx.y * 64;
    int t = threadIdx.x;
#pragma unroll
    for (int i = 0; i < 16; i++) {
        int idx = t + i * 256;
        int rr = idx >> 6, cc = idx & 63;
        tile[rr][cc] = f2b(W[(size_t)(r0 + rr) * C + c0 + cc]);
    }
    __syncthreads();
#pragma unroll
    for (int i = 0; i < 16; i++) {
        int idx = t + i * 256;
        int rr = idx >> 6, cc = idx & 63;
        out[(size_t)(c0 + rr) * R + r0 + cc] = tile[cc][rr];
    }
}

__global__ void concat_bias(const float* __restrict__ bq, const float* __restrict__ bk,
                            const float* __restrict__ bv, float* __restrict__ out) {
    int i = blockIdx.x * 256 + threadIdx.x;
    if (i >= 1536) return;
    out[i] = i < 512 ? bq[i] : (i < 1024 ? bk[i - 512] : bv[i - 1024]);
}

// V (rows of QKV, stride ldv) -> tiled VT: out[(kv>>5)*(HID*32) + col*32 + (kv&31)]
// vectorized bf16x8 on both global sides
__global__ __launch_bounds__(256) void transpose_v_tiled(const u16* __restrict__ in, int ldv,
                                                         u16* __restrict__ out) {
    __shared__ u16 tl[64][72];
    int c0 = blockIdx.x * 64;   // col block (HID)
    int r0 = blockIdx.y * 64;   // kv block (NROW)
    int t = threadIdx.x;
#pragma unroll
    for (int i = 0; i < 2; i++) {
        int idx = t + i * 256;          // 0..511
        int rr = idx >> 3, ck = idx & 7;
        bf16x8 v = *(const bf16x8*)(in + (size_t)(r0 + rr) * ldv + c0 + ck * 8);
#pragma unroll
        for (int j = 0; j < 8; j++) tl[ck * 8 + j][rr] = ((u16*)&v)[j];
    }
    __syncthreads();
#pragma unroll
    for (int i = 0; i < 2; i++) {
        int idx = t + i * 256;
        int col = idx >> 3, ch = idx & 7;
        int kv = ch * 8;
        bf16x8 v;
#pragma unroll
        for (int j = 0; j < 8; j++) ((u16*)&v)[j] = tl[col][kv + j];
        *(bf16x8*)(out + (size_t)((r0 + kv) >> 5) * (HID * 32) +
                   (size_t)(c0 + col) * 32 + (kv & 31)) = v;
    }
}

// ---------------- GEMM 128x128, BK=64, LDS double-buffered ----------------
__global__ __launch_bounds__(256, 2) void gemm128(const u16* __restrict__ A, int lda,
                                                  const u16* __restrict__ Bt,
                                                  const float* __restrict__ bias,
                                                  float* __restrict__ outF,
                                                  u16* __restrict__ outH, int ldo,
                                                  int relu, int K) {
    __shared__ u16 Ald[2][8192];
    __shared__ u16 Bld[2][8192];
    int lane = threadIdx.x & 63, wave = threadIdx.x >> 6;
    int l15 = lane & 15, lg = lane >> 4;
    int wr = wave >> 1, wc = wave & 1;
    int row0 = blockIdx.y * 128, col0 = blockIdx.x * 128;

    auto stage = [&](int buf, int kk) {
#pragma unroll
        for (int i = 0; i < 4; i++) {
            int seg = wave * 4 + i;
            int row = seg * 8 + (lane >> 3);
            int c = lane & 7;
            int csw = c ^ (row & 7);
            gll16(A + (size_t)(row0 + row) * lda + kk + csw * 8,
                  &Ald[buf][seg * 512 + lane * 8]);
            gll16(Bt + (size_t)(col0 + row) * K + kk + csw * 8,
                  &Bld[buf][seg * 512 + lane * 8]);
        }
    };

    f32x4 acc[4][4];
#pragma unroll
    for (int i = 0; i < 4; i++)
#pragma unroll
        for (int j = 0; j < 4; j++) acc[i][j] = zero4();

    stage(0, 0);
    asm volatile("s_waitcnt vmcnt(0)" ::: "memory");
    __syncthreads();

    int nk = K >> 6;
    for (int kt = 0; kt < nk; kt++) {
        int buf = kt & 1;
        if (kt + 1 < nk) stage(buf ^ 1, (kt + 1) * 64);
#pragma unroll
        for (int ks = 0; ks < 2; ks++) {
            bf16x8 af[4], bfr[4];
#pragma unroll
            for (int i = 0; i < 4; i++) {
                int row = wr * 64 + i * 16 + l15;
                af[i] = *(const bf16x8*)&Ald[buf][row * 64 + (((ks * 4 + lg) ^ (row & 7)) * 8)];
            }
#pragma unroll
            for (int j = 0; j < 4; j++) {
                int row = wc * 64 + j * 16 + l15;
                bfr[j] = *(const bf16x8*)&Bld[buf][row * 64 + (((ks * 4 + lg) ^ (row & 7)) * 8)];
            }
            __builtin_amdgcn_s_setprio(1);
#pragma unroll
            for (int i = 0; i < 4; i++)
#pragma unroll
                for (int j = 0; j < 4; j++)
                    acc[i][j] = __builtin_amdgcn_mfma_f32_16x16x32_bf16(af[i], bfr[j],
                                                                       acc[i][j], 0, 0, 0);
            __builtin_amdgcn_s_setprio(0);
        }
        asm volatile("s_waitcnt vmcnt(0)" ::: "memory");
        __syncthreads();
    }
#pragma unroll
    for (int j = 0; j < 4; j++) {
        int col = col0 + wc * 64 + j * 16 + l15;
        float bv = bias[col];
#pragma unroll
        for (int i = 0; i < 4; i++) {
#pragma unroll
            for (int r = 0; r < 4; r++) {
                int row = row0 + wr * 64 + i * 16 + lg * 4 + r;
                float v = acc[i][j][r] + bv;
                if (relu) v = fmaxf(v, 0.f);
                size_t o = (size_t)row * ldo + col;
                if (outF) outF[o] = v;
                if (outH) outH[o] = f2b(v);
            }
        }
    }
}

// ---------------- split-KV flash attention v4 ----------------
// 512 blocks = 128 qb x 4 splits; 4 waves x 16 q rows = 64 rows/block; KVB=32.
// K LDS-staged (dbuf) in LINEAR lane-order layout (conflict-free ds_read_b128):
//   byte(ks,half,lane) = ks*2048 + half*1024 + lane*16
//   holds K[kv0 + half*16 + (lane&15)][ks*32 + (lane>>4)*8 .. +7]
// P per-wave LDS in linear lane-order layout. V from tiled-VT global (L1 path).
__global__ __launch_bounds__(256, 2) void attn_kernel(const u16* __restrict__ QKV,
                                                      const u16* __restrict__ VTt,
                                                      const u32* __restrict__ bits,
                                                      u16* __restrict__ Opart,
                                                      float* __restrict__ Mpart,
                                                      float* __restrict__ Lpart) {
    extern __shared__ char smem[];
    u16* Klds = (u16*)smem;                               // 2 x 32KB
    int lane = threadIdx.x & 63, wave = threadIdx.x >> 6;
    u16* myp = (u16*)(smem + 65536) + wave * 512;         // per-wave 1KB P
    int l15 = lane & 15, lg = lane >> 4;
    int s = blockIdx.x & 3;
    int qb = blockIdx.x >> 2;
    int qbase = qb * 64 + wave * 16;
    const u16* Kg = QKV + 512;

    // Q preload: 16 A-frags (64 VGPR)
    bf16x8 qf[16];
    {
        const u16* qp = QKV + (size_t)(qbase + l15) * LDQ + lg * 8;
#pragma unroll
        for (int ks = 0; ks < 16; ks++) qf[ks] = *(const bf16x8*)(qp + ks * 32);
    }

    f32x4 acc[32];
#pragma unroll
    for (int i = 0; i < 32; i++) acc[i] = zero4();
    float m[4] = {-1e30f, -1e30f, -1e30f, -1e30f};
    float lsum[4] = {0.f, 0.f, 0.f, 0.f};
    const float scale = 0.04419417382415922f;  // 1/sqrt(512)
    int kvbeg = s * KVCH;

    // stage 32KB K tile: 32 segments of 1KB; 4 waves x 8 segs; LDS linear per lane
    auto STAGE = [&](int buf, int kv0) {
#pragma unroll
        for (int i = 0; i < 8; i++) {
            int seg = wave * 8 + i;
            gll16(Kg + (size_t)(kv0 + (seg & 1) * 16 + (lane & 15)) * LDQ +
                      (seg >> 1) * 32 + (lane >> 4) * 8,
                  Klds + buf * 16384 + seg * 512 + lane * 8);
        }
    };

    STAGE(0, kvbeg);
    asm volatile("s_waitcnt vmcnt(0)" ::: "memory");
    __syncthreads();

    for (int t = 0; t < KVCH / KVB; ++t) {
        int kv0 = kvbeg + t * KVB;
        int buf = t & 1;
        if (t + 1 < KVCH / KVB) STAGE(buf ^ 1, kv0 + KVB);
        const u16* kb = Klds + buf * 16384;

        // ---- S = Q(16x512) @ K^T(512x32) ----
        f32x4 sf[2];
        sf[0] = zero4(); sf[1] = zero4();
        __builtin_amdgcn_s_setprio(1);
#pragma unroll
        for (int ks = 0; ks < 16; ks++) {
            bf16x8 b0 = *(const bf16x8*)(kb + ks * 1024 + lane * 8);
            bf16x8 b1 = *(const bf16x8*)(kb + ks * 1024 + 512 + lane * 8);
            sf[0] = __builtin_amdgcn_mfma_f32_16x16x32_bf16(qf[ks], b0, sf[0], 0, 0, 0);
            sf[1] = __builtin_amdgcn_mfma_f32_16x16x32_bf16(qf[ks], b1, sf[1], 0, 0, 0);
        }
        __builtin_amdgcn_s_setprio(0);

        // ---- mask + online softmax (defer-max THR=8) ----
        u32 w0[4];
#pragma unroll
        for (int r = 0; r < 4; r++)
            w0[r] = bits[(size_t)(qbase + lg * 4 + r) * 256 + (kv0 >> 5)];
        float pvv[2][4];
        float mx[4] = {-1e30f, -1e30f, -1e30f, -1e30f};
#pragma unroll
        for (int f = 0; f < 2; f++) {
            int c = f * 16 + l15;
#pragma unroll
            for (int r = 0; r < 4; r++) {
                bool bit = (w0[r] >> c) & 1u;
                float sv = bit ? sf[f][r] * scale : -1e30f;
                pvv[f][r] = sv;
                mx[r] = fmaxf(mx[r], sv);
            }
        }
#pragma unroll
        for (int r = 0; r < 4; r++) {
#pragma unroll
            for (int off = 8; off; off >>= 1)
                mx[r] = fmaxf(mx[r], __shfl_xor(mx[r], off, 64));
        }
        bool need = false;
#pragma unroll
        for (int r = 0; r < 4; r++) need |= (mx[r] > m[r] + 8.0f);
        if (__any(need ? 1 : 0)) {
            float csc[4];
#pragma unroll
            for (int r = 0; r < 4; r++) {
                float mn = fmaxf(m[r], mx[r]);
                csc[r] = __expf(m[r] - mn);
                m[r] = mn;
                lsum[r] *= csc[r];
            }
#pragma unroll
            for (int i = 0; i < 32; i++) {
                f32x4 a = acc[i];
                a[0] *= csc[0]; a[1] *= csc[1]; a[2] *= csc[2]; a[3] *= csc[3];
                acc[i] = a;
            }
        }
#pragma unroll
        for (int f = 0; f < 2; f++)
#pragma unroll
            for (int r = 0; r < 4; r++)
                pvv[f][r] = (pvv[f][r] < -1e29f) ? 0.f : __expf(pvv[f][r] - m[r]);
#pragma unroll
        for (int r = 0; r < 4; r++) {
            float rs = pvv[0][r] + pvv[1][r];
#pragma unroll
            for (int off = 8; off; off >>= 1) rs += __shfl_xor(rs, off, 64);
            lsum[r] += rs;
        }

        // ---- P (D-layout) -> per-wave LDS (linear layout) -> A-frag ----
        // P[row][col] at u16 idx (col>>3)*128 + row*8 + (col&7)
#pragma unroll
        for (int f = 0; f < 2; f++)
#pragma unroll
            for (int r = 0; r < 4; r++)
                myp[(f * 2 + (l15 >> 3)) * 128 + (lg * 4 + r) * 8 + (l15 & 7)] = f2b(pvv[f][r]);
        asm volatile("s_waitcnt lgkmcnt(0)" ::: "memory");
        __builtin_amdgcn_sched_barrier(0);
        bf16x8 pa = *(const bf16x8*)(myp + lane * 8);

        // ---- O += P(16x32) @ V(32x512), V from tiled-VT (L1), prefetch 2 ----
        const u16* vb = VTt + (size_t)(kv0 >> 5) * (HID * 32);
        bf16x8 v_c = *(const bf16x8*)(vb + (size_t)l15 * 32 + lg * 8);
        bf16x8 v_n = *(const bf16x8*)(vb + (size_t)(16 + l15) * 32 + lg * 8);
        __builtin_amdgcn_s_setprio(1);
#pragma unroll
        for (int cf = 0; cf < 32; ++cf) {
            bf16x8 v_f = v_c;
            if (cf + 2 < 32)
                v_f = *(const bf16x8*)(vb + (size_t)((cf + 2) * 16 + l15) * 32 + lg * 8);
            acc[cf] = __builtin_amdgcn_mfma_f32_16x16x32_bf16(pa, v_c, acc[cf], 0, 0, 0);
            v_c = v_n; v_n = v_f;
        }
        __builtin_amdgcn_s_setprio(0);

        asm volatile("s_waitcnt vmcnt(0)" ::: "memory");
        __syncthreads();
    }

    // ---- write partials ----
    if (l15 == 0) {
#pragma unroll
        for (int r = 0; r < 4; r++) {
            size_t o = (size_t)s * NROW + qbase + lg * 4 + r;
            Mpart[o] = m[r];
            Lpart[o] = lsum[r];
        }
    }
#pragma unroll
    for (int cf = 0; cf < 32; cf++) {
        int col = cf * 16 + l15;
#pragma unroll
        for (int r = 0; r < 4; r++) {
            size_t row = (size_t)s * NROW + qbase + lg * 4 + r;
            Opart[row * HID + col] = f2b(acc[cf][r]);
        }
    }
}

// combine 4 split partials -> O16
__global__ __launch_bounds__(256) void attn_combine(const u16* __restrict__ Opart,
                                                    const float* __restrict__ Mpart,
                                                    const float* __restrict__ Lpart,
                                                    u16* __restrict__ O16) {
    int idx = blockIdx.x * 256 + threadIdx.x;
    int row = idx >> 6;
    int c8 = (idx & 63) << 3;
    float ms[NSPLIT], M = -1e30f;
#pragma unroll
    for (int s = 0; s < NSPLIT; s++) {
        ms[s] = Mpart[(size_t)s * NROW + row];
        M = fmaxf(M, ms[s]);
    }
    float w[NSPLIT], L = 0.f;
#pragma unroll
    for (int s = 0; s < NSPLIT; s++) {
        w[s] = __expf(ms[s] - M);
        L += Lpart[(size_t)s * NROW + row] * w[s];
    }
    float inv = 1.f / L;
    float o[8];
#pragma unroll
    for (int j = 0; j < 8; j++) o[j] = 0.f;
#pragma unroll
    for (int s = 0; s < NSPLIT; s++) {
        bf16x8 p = *(const bf16x8*)(Opart + ((size_t)s * NROW + row) * HID + c8);
#pragma unroll
        for (int j = 0; j < 8; j++) o[j] += (float)p[j] * w[s];
    }
    bf16x8 res;
#pragma unroll
    for (int j = 0; j < 8; j++) {
        u16 b = f2b(o[j] * inv);
        res[j] = *(bf16_t*)&b;
    }
    *(bf16x8*)(O16 + (size_t)row * HID + c8) = res;
}

// ---------------- layernorm(a+b) ----------------
__global__ __launch_bounds__(256) void ln_add(const float* __restrict__ a,
                                              const float* __restrict__ b,
                                              const float* __restrict__ g,
                                              const float* __restrict__ be,
                                              float* __restrict__ outF,
                                              u16* __restrict__ outH) {
    int row = blockIdx.x, t = threadIdx.x;
    const float* ar = a + (size_t)row * HID;
    const float* br = b + (size_t)row * HID;
    float x0 = ar[t] + br[t];
    float x1 = ar[t + 256] + br[t + 256];
    float s = x0 + x1, s2 = x0 * x0 + x1 * x1;
#pragma unroll
    for (int off = 32; off; off >>= 1) {
        s += __shfl_xor(s, off, 64);
        s2 += __shfl_xor(s2, off, 64);
    }
    __shared__ float ls[4], ls2[4];
    int wv = t >> 6, ln = t & 63;
    if (ln == 0) { ls[wv] = s; ls2[wv] = s2; }
    __syncthreads();
    float S = ls[0] + ls[1] + ls[2] + ls[3];
    float S2 = ls2[0] + ls2[1] + ls2[2] + ls2[3];
    float mu = S * (1.f / 512.f);
    float var = S2 * (1.f / 512.f) - mu * mu;
    float inv = rsqrtf(var + 1e-5f);
    float y0 = (x0 - mu) * inv * g[t] + be[t];
    float y1 = (x1 - mu) * inv * g[t + 256] + be[t + 256];
    size_t o = (size_t)row * HID + t;
    if (outF) { outF[o] = y0; outF[o + 256] = y1; }
    if (outH) { outH[o] = f2b(y0); outH[o + 256] = f2b(y1); }
}

// ---------------- logits ----------------
__global__ __launch_bounds__(256) void logits_k(const u16* __restrict__ hfin,
                                                const float* __restrict__ Ws,
                                                const float* __restrict__ bs,
                                                float* __restrict__ out) {
    int row = blockIdx.x * 4 + (threadIdx.x >> 6);
    int lane = threadIdx.x & 63;
    const u16* hp = hfin + (size_t)row * HID + lane * 8;
    float sum = 0.f;
#pragma unroll
    for (int j = 0; j < 8; j++) sum += b2f(hp[j]) * Ws[lane * 8 + j];
#pragma unroll
    for (int off = 32; off; off >>= 1) sum += __shfl_xor(sum, off, 64);
    if (lane == 0) out[row] = sum + bs[0];
}

// ---------------- host launcher ----------------
extern "C" void kernel_launch(void* const* d_in, const int* in_sizes, int n_in,
                              void* d_out, int out_size, void* d_ws, size_t ws_size,
                              hipStream_t stream) {
    const float* x   = (const float*)d_in[0];
    const void*  adj = d_in[1];
    const float* Win = (const float*)d_in[2];
    const float* b_in= (const float*)d_in[3];
    const float* Wq  = (const float*)d_in[4];
    const float* bq  = (const float*)d_in[5];
    const float* Wk  = (const float*)d_in[6];
    const float* bk  = (const float*)d_in[7];
    const float* Wv  = (const float*)d_in[8];
    const float* bv  = (const float*)d_in[9];
    const float* Wo  = (const float*)d_in[10];
    const float* bo  = (const float*)d_in[11];
    const float* Ws  = (const float*)d_in[12];
    const float* bs  = (const float*)d_in[13];
    const float* g1  = (const float*)d_in[14];
    const float* be1 = (const float*)d_in[15];
    const float* g2  = (const float*)d_in[16];
    const float* be2 = (const float*)d_in[17];
    const float* Wf1 = (const float*)d_in[18];
    const float* bf1 = (const float*)d_in[19];
    const float* Wf2 = (const float*)d_in[20];
    const float* bf2 = (const float*)d_in[21];

    char* ws = (char*)d_ws;
    const size_t MB = 1u << 20;
    const size_t OFF_PART = 0;            // 32MB partial O (attn..combine) overlays:
    const size_t OFF_X16  = 0;            //   4MB x bf16   (dead after h-gemm)
    const size_t OFF_H16  = 4 * MB;       //   8MB h bf16   (dead after qkv-gemm)
    const size_t OFF_HN32 = 12 * MB;      //  16MB ln1 f32  (written after combine)
    const size_t OFF_HN16 = 28 * MB;      //   8MB ln1 bf16
    const size_t OFF_FF1  = 4 * MB;       //   8MB (overlays dead H16)
    const size_t OFF_HF32 = 36 * MB;      //  16MB h f32 (h-gemm .. LN1)
    const size_t OFF_QKV  = 52 * MB;      //  24MB fused qkv bf16 (dead after attn)
    const size_t OFF_OP32 = 52 * MB;      //  16MB o-proj f32 (overlays dead QKV)
    const size_t OFF_FF2  = 52 * MB;      //  16MB (overlays dead OP32)
    const size_t OFF_VT   = 76 * MB;      //   8MB tiled VT (dead after attn)
    const size_t OFF_HFIN = 76 * MB;      //   8MB final hidden (overlays dead VT)
    const size_t OFF_H2   = 84 * MB;      //   8MB attn out bf16
    const size_t OFF_BITS = 92 * MB;      //   8MB adjacency bitmask
    size_t off = 100 * MB;
    const size_t OFF_WINT = off;  off += 262144;
    const size_t OFF_QKVT = off;  off += 1572864;
    const size_t OFF_WOT  = off;  off += 524288;
    const size_t OFF_WF1T = off;  off += 524288;
    const size_t OFF_WF2T = off;  off += 524288;
    const size_t OFF_BQKV = off;  off += 8192;
    const size_t OFF_MODE = off;  off += 4096;
    const size_t OFF_MPART= off;  off += 131072;
    const size_t OFF_LPART= off;  off += 131072;

    u16* pX16   = (u16*)(ws + OFF_X16);
    u16* pH16   = (u16*)(ws + OFF_H16);
    float* pHN32= (float*)(ws + OFF_HN32);
    u16* pHN16  = (u16*)(ws + OFF_HN16);
    u16* pFF1   = (u16*)(ws + OFF_FF1);
    float* pHF32= (float*)(ws + OFF_HF32);
    u16* pQKV   = (u16*)(ws + OFF_QKV);
    float* pOP32= (float*)(ws + OFF_OP32);
    float* pFF2 = (float*)(ws + OFF_FF2);
    u16* pVT    = (u16*)(ws + OFF_VT);
    u16* pHFIN  = (u16*)(ws + OFF_HFIN);
    u16* pH2    = (u16*)(ws + OFF_H2);
    u32* pBits  = (u32*)(ws + OFF_BITS);
    u16* pPart  = (u16*)(ws + OFF_PART);
    u16* pWinT  = (u16*)(ws + OFF_WINT);
    u16* pQKVT  = (u16*)(ws + OFF_QKVT);
    u16* pWoT   = (u16*)(ws + OFF_WOT);
    u16* pWf1T  = (u16*)(ws + OFF_WF1T);
    u16* pWf2T  = (u16*)(ws + OFF_WF2T);
    float* pBqkv= (float*)(ws + OFF_BQKV);
    int* pMode  = (int*)(ws + OFF_MODE);
    float* pMp  = (float*)(ws + OFF_MPART);
    float* pLp  = (float*)(ws + OFF_LPART);

    // adjacency bitmask
    sniff_adj<<<1, 64, 0, stream>>>((const u32*)adj, pMode);
    build_bits<<<NROW, 256, 0, stream>>>(adj, pMode, pBits);

    // conversions
    convert_f32_bf16<<<(NROW * DIN) / 256, 256, 0, stream>>>(x, pX16, NROW * DIN);
    transpose_wt<<<dim3(8, 4), 256, 0, stream>>>(Win, pWinT, DIN, HID);
    transpose_wt<<<dim3(8, 8), 256, 0, stream>>>(Wq, pQKVT, HID, HID);
    transpose_wt<<<dim3(8, 8), 256, 0, stream>>>(Wk, pQKVT + 512 * 512, HID, HID);
    transpose_wt<<<dim3(8, 8), 256, 0, stream>>>(Wv, pQKVT + 2 * 512 * 512, HID, HID);
    transpose_wt<<<dim3(8, 8), 256, 0, stream>>>(Wo, pWoT, HID, HID);
    transpose_wt<<<dim3(8, 8), 256, 0, stream>>>(Wf1, pWf1T, HID, HID);
    transpose_wt<<<dim3(8, 8), 256, 0, stream>>>(Wf2, pWf2T, HID, HID);
    concat_bias<<<6, 256, 0, stream>>>(bq, bk, bv, pBqkv);

    // h = x @ Win + b_in (f32 + bf16)
    gemm128<<<dim3(4, 64), 256, 0, stream>>>(pX16, DIN, pWinT, b_in,
                                             pHF32, pH16, HID, 0, DIN);
    // qkv = h @ [Wq|Wk|Wv] (bf16, fused, ldo=1536)
    gemm128<<<dim3(12, 64), 256, 0, stream>>>(pH16, HID, pQKVT, pBqkv,
                                              nullptr, pQKV, LDQ, 0, HID);
    // tiled vt
    transpose_v_tiled<<<dim3(HID / 64, NROW / 64), 256, 0, stream>>>(pQKV + 1024, LDQ, pVT);
    // attention (split-KV) + combine
    attn_kernel<<<128 * NSPLIT, 256, 69632, stream>>>(pQKV, pVT, pBits, pPart, pMp, pLp);
    attn_combine<<<NROW * HID / (256 * 8), 256, 0, stream>>>(pPart, pMp, pLp, pH2);
    // o-proj (f32)
    gemm128<<<dim3(4, 64), 256, 0, stream>>>(pH2, HID, pWoT, bo,
                                             pOP32, nullptr, HID, 0, HID);
    // LN1
    ln_add<<<NROW, 256, 0, stream>>>(pHF32, pOP32, g1, be1, pHN32, pHN16);
    // ff1 = relu(hn @ Wf1 + bf1)
    gemm128<<<dim3(4, 64), 256, 0, stream>>>(pHN16, HID, pWf1T, bf1,
                                             nullptr, pFF1, HID, 1, HID);
    // ff2
    gemm128<<<dim3(4, 64), 256, 0, stream>>>(pFF1, HID, pWf2T, bf2,
                                             pFF2, nullptr, HID, 0, HID);
    // LN2 -> bf16
    ln_add<<<NROW, 256, 0, stream>>>(pHN32, pFF2, g2, be2, nullptr, pHFIN);
    // logits
    logits_k<<<NROW / 4, 256, 0, stream>>>(pHFIN, Ws, bs, (float*)d_out);
}